// Round 8
// baseline (2049.376 us; speedup 1.0000x reference)
//
#include <hip/hip_runtime.h>
#include <hip/hip_bf16.h>

#define N_USERS 20000
#define N_ITEMS 30000
#define NTOT    50000
#define DIM     64
#define EXTRA_D 1152
#define E_EDGES 500000
#define NC      100
#define KTOT    1216
#define KSTEPS  38
#define PPART   16
#define SPART   128

// prep_edges block ranges
#define B_FEI  1954
#define B_W1   608
#define B_W2   32
#define B_CEI  256
#define PREP_GRID (B_FEI+B_W1+B_W2+B_CEI)   // 2850

// fus_scan block ranges
#define FUS_BLKS ((N_ITEMS+127)/128)     // 235
#define SCAN1_BLKS ((NTOT+1023)/1024)    // 49
#define B_COPY 1250
#define B_CC   64
#define FUS_GRID (FUS_BLKS+SCAN1_BLKS+1+B_COPY+B_CC)  // 1599

#define SC3_BLKS ((NTOT+255)/256)        // 196
#define FILL_BLKS ((E_EDGES+255)/256)    // 1954

// persistent tail kernel: 1024 blocks x 4 waves; capacity 4 blk/CU x 256 CU = 1024
#define GRID_C 1024
#define NSTRIDE (GRID_C*4)               // 4096 wave-slots

typedef __attribute__((ext_vector_type(8))) short short8;
typedef __attribute__((ext_vector_type(4))) float v4f;

// ---------------- helpers ----------------
__device__ __forceinline__ float wred_sum(float v){
#pragma unroll
  for(int o=32;o;o>>=1) v += __shfl_xor(v,o,64);
  return v;
}
__device__ __forceinline__ int wred_sumi(int v){
#pragma unroll
  for(int o=32;o;o>>=1) v += __shfl_xor(v,o,64);
  return v;
}
__device__ __forceinline__ float lrelu(float x){ return x>0.f? x : 0.2f*x; }
__device__ __forceinline__ short f2bf(float f){
  unsigned u=__float_as_uint(f);
  unsigned r=(u + 0x7FFFu + ((u>>16)&1u))>>16;
  return (short)r;
}
__device__ __forceinline__ unsigned pack_bf2(float x, float y){
  return (unsigned)(unsigned short)f2bf(x) | ((unsigned)(unsigned short)f2bf(y)<<16);
}

// manual grid barrier (all GRID_C blocks co-resident by construction).
// arrive: per-block flag store (no contention); block 0 polls flags, then releases.
__device__ __forceinline__ void grid_bar(int* __restrict__ flags, int* __restrict__ rel, int gen){
  __syncthreads();
  const int t=threadIdx.x;
  if(t==0){
    __threadfence();
    __hip_atomic_store(&flags[blockIdx.x], gen, __ATOMIC_RELEASE, __HIP_MEMORY_SCOPE_AGENT);
  }
  if(blockIdx.x==0){
    long guard=0;
    for(;;){
      int ok=1;
#pragma unroll
      for(int i=0;i<GRID_C/256;i++){
        if(__hip_atomic_load(&flags[t+i*256], __ATOMIC_ACQUIRE, __HIP_MEMORY_SCOPE_AGENT) < gen) ok=0;
      }
      if(__syncthreads_and(ok)) break;
      if(++guard > 200000000L) break;
      __builtin_amdgcn_s_sleep(16);
    }
    if(t==0) __hip_atomic_store(rel, gen, __ATOMIC_RELEASE, __HIP_MEMORY_SCOPE_AGENT);
  } else {
    if(t==0){
      long guard=0;
      while(__hip_atomic_load(rel, __ATOMIC_ACQUIRE, __HIP_MEMORY_SCOPE_AGENT) < gen){
        __builtin_amdgcn_s_sleep(16);
        if(++guard > 200000000L) break;
      }
    }
    __syncthreads();
  }
}

// ---------------- K2: prep_edges ----------------
__global__ __launch_bounds__(256) void prep_edges_kernel(
    const float* __restrict__ w1, short* __restrict__ w1t,
    const float* __restrict__ w2, short* __restrict__ w2t,
    const int* __restrict__ ca,
    const int* __restrict__ fei, const float* __restrict__ fea,
    int* __restrict__ cnt_dst, int* __restrict__ clflag, int* __restrict__ degI,
    float2* __restrict__ partA,
    const int* __restrict__ cei, const float* __restrict__ cea, int Ec,
    int* __restrict__ ccnt_dst, float2* __restrict__ partB)
{
  __shared__ int hist[NC];
  __shared__ float2 w4[4];
  const int b=blockIdx.x, t=threadIdx.x;
  const int lane=t&63, wv=t>>6;
  if(b < B_FEI){
    int e = b*256+t;
    float a0=0.f,a1=0.f;
    if(e<E_EDGES){
      int s=fei[e], d=fei[E_EDGES+e];
      atomicAdd(&cnt_dst[d],1);
      int cs=ca[s];
      if(cs==ca[d]){ clflag[cs]=1; atomicAdd(&degI[d],1); }
      float2 v=*(const float2*)(fea+2*e);
      a0=v.x; a1=v.y;
    }
    a0=wred_sum(a0); a1=wred_sum(a1);
    if(lane==0) w4[wv]=make_float2(a0,a1);
    __syncthreads();
    if(t==0){ float2 r=w4[0]; for(int i=1;i<4;i++){r.x+=w4[i].x; r.y+=w4[i].y;} partA[b]=r; }
  } else if(b < B_FEI+B_W1){
    int i = (b-B_FEI)*256+t;               // 608*256 == 1216*128 exactly
    int row = i>>7, n = i&127;             // coalesced read w1[i]
    int s = row>>5, kk = row&31;
    w1t[s*4096 + n*32 + kk] = f2bf(w1[i]);
  } else if(b < B_FEI+B_W1+B_W2){
    int i = (b-B_FEI-B_W1)*256+t;          // 32*256 == 8192 exactly
    int n = i>>6, c = i&63;                // coalesced read w2[i]
    w2t[c*128 + n] = f2bf(w2[i]);
  } else {
    int bb = b-(B_FEI+B_W1+B_W2);
    for(int i=t;i<NC;i+=256) hist[i]=0;
    __syncthreads();
    float a0=0.f,a1=0.f;
    for(int e=bb*256+t; e<Ec; e+=B_CEI*256){
      atomicAdd(&hist[cei[Ec+e]],1);
      float2 v=*(const float2*)(cea+2*e);
      a0+=v.x; a1+=v.y;
    }
    a0=wred_sum(a0); a1=wred_sum(a1);
    if(lane==0) w4[wv]=make_float2(a0,a1);
    __syncthreads();
    if(t==0){ float2 r=w4[0]; for(int i=1;i<4;i++){r.x+=w4[i].x; r.y+=w4[i].y;} partB[bb]=r; }
    for(int i=t;i<NC;i+=256) if(hist[i]) atomicAdd(&ccnt_dst[i],hist[i]);
  }
}

// ---------------- K3: fusion MFMA | scan1 | prep_small | user copy | ccnt ----------------
__global__ __launch_bounds__(256) void fus_scan_kernel(
    const float* __restrict__ item, const float* __restrict__ extra,
    const short* __restrict__ w1t, const float* __restrict__ b1,
    const short* __restrict__ w2t, const float* __restrict__ b2,
    float* __restrict__ X,
    const float2* __restrict__ partA, const float2* __restrict__ partB, int Ec,
    const float* __restrict__ cg_le, const float* __restrict__ cg_ae,
    const float* __restrict__ gat_le, const float* __restrict__ gat_ae,
    float* __restrict__ coefs,
    const int* __restrict__ cnt_dst, int* __restrict__ incl, int* __restrict__ bsum,
    const float* __restrict__ u, const int* __restrict__ ca, int* __restrict__ ccnt)
{
  __shared__ short As[128*40];
  __shared__ short Bs[128*40];
  __shared__ short Hs[128*136];
  __shared__ int ssc[256];
  const int tid = threadIdx.x;
  const int b = blockIdx.x;
  if(b < FUS_BLKS){
    const int blk = b;
    const int w = tid>>6, lane = tid&63, quad = lane>>4, l16 = lane&15;
    const int mw = w&1, nw = w>>1;

    v4f acc[4][4];
#pragma unroll
    for(int a=0;a<4;a++)
#pragma unroll
      for(int c=0;c<4;c++) acc[a][c] = (v4f){0.f,0.f,0.f,0.f};

    const int arow = tid>>3;
    const int aoff = (tid&7)*4;
    for(int s=0;s<KSTEPS;s++){
      const int k0 = s*32;
#pragma unroll
      for(int it=0;it<4;it++){
        int r = arow + it*32;
        int col = k0 + aoff;
        int gr = blk*128 + r; if(gr >= N_ITEMS) gr = N_ITEMS-1;
        float4 v = (col < DIM) ? *(const float4*)(item + (size_t)gr*DIM + col)
                               : *(const float4*)(extra + (size_t)gr*EXTRA_D + (col-DIM));
        short4 bv; bv.x=f2bf(v.x); bv.y=f2bf(v.y); bv.z=f2bf(v.z); bv.w=f2bf(v.w);
        *(short4*)&As[r*40 + aoff] = bv;
      }
#pragma unroll
      for(int it=0;it<2;it++){
        int idx = tid + it*256;
        int4 v = *(const int4*)(w1t + (size_t)s*4096 + idx*8);
        int n = idx>>2, kk = (idx&3)*8;
        *(int4*)&Bs[n*40 + kk] = v;
      }
      __syncthreads();
      short8 af[4], bf_[4];
#pragma unroll
      for(int i=0;i<4;i++){
        int m = mw*64 + i*16 + l16;
        af[i]  = *(const short8*)&As[m*40 + quad*8];
        int n = nw*64 + i*16 + l16;
        bf_[i] = *(const short8*)&Bs[n*40 + quad*8];
      }
#pragma unroll
      for(int mi=0;mi<4;mi++)
#pragma unroll
        for(int ni=0;ni<4;ni++)
          acc[mi][ni] = __builtin_amdgcn_mfma_f32_16x16x32_bf16(af[mi], bf_[ni], acc[mi][ni], 0,0,0);
      __syncthreads();
    }

#pragma unroll
    for(int ni=0;ni<4;ni++){
      int n = nw*64 + ni*16 + l16;
      float bias = b1[n];
#pragma unroll
      for(int mi=0;mi<4;mi++){
        int mbase = mw*64 + mi*16 + quad*4;
#pragma unroll
        for(int r=0;r<4;r++){
          float hv = fmaxf(acc[mi][ni][r] + bias, 0.f);
          Hs[(mbase+r)*136 + n] = f2bf(hv);
        }
      }
    }
    __syncthreads();

    v4f acc2[2][4];
#pragma unroll
    for(int a=0;a<2;a++)
#pragma unroll
      for(int c=0;c<4;c++) acc2[a][c] = (v4f){0.f,0.f,0.f,0.f};
#pragma unroll
    for(int ks=0;ks<4;ks++){
      short8 ha[2];
#pragma unroll
      for(int mi=0;mi<2;mi++){
        int m = w*32 + mi*16 + l16;
        ha[mi] = *(const short8*)&Hs[m*136 + ks*32 + quad*8];
      }
#pragma unroll
      for(int ni=0;ni<4;ni++){
        int c = ni*16 + l16;
        short8 wb = *(const short8*)(w2t + c*128 + ks*32 + quad*8);
#pragma unroll
        for(int mi=0;mi<2;mi++)
          acc2[mi][ni] = __builtin_amdgcn_mfma_f32_16x16x32_bf16(ha[mi], wb, acc2[mi][ni], 0,0,0);
      }
    }
#pragma unroll
    for(int ni=0;ni<4;ni++){
      int c = ni*16 + l16;
      float b2v = b2[c];
#pragma unroll
      for(int mi=0;mi<2;mi++){
        int mbase = w*32 + mi*16 + quad*4;
#pragma unroll
        for(int r=0;r<4;r++){
          int row = blk*128 + mbase + r;
          if(row < N_ITEMS) X[(size_t)(N_USERS+row)*64 + c] = acc2[mi][ni][r] + b2v;
        }
      }
    }
  } else if(b < FUS_BLKS+SCAN1_BLKS){
    int sb = b-FUS_BLKS;
    int base = sb*1024 + tid*4;
    int a0=(base  <NTOT)?cnt_dst[base  ]+1:0;
    int a1=(base+1<NTOT)?cnt_dst[base+1]+1:0;
    int a2=(base+2<NTOT)?cnt_dst[base+2]+1:0;
    int a3=(base+3<NTOT)?cnt_dst[base+3]+1:0;
    int l1=a0+a1, l2=l1+a2, l3=l2+a3;
    ssc[tid]=l3; __syncthreads();
    for(int off=1;off<256;off<<=1){
      int v=(tid>=off)?ssc[tid-off]:0; __syncthreads();
      ssc[tid]+=v; __syncthreads();
    }
    int prev = tid? ssc[tid-1]:0;
    if(base  <NTOT) incl[base  ]=prev+a0;
    if(base+1<NTOT) incl[base+1]=prev+l1;
    if(base+2<NTOT) incl[base+2]=prev+l2;
    if(base+3<NTOT) incl[base+3]=prev+l3;
    if(tid==255) bsum[sb]=ssc[255];
  } else if(b == FUS_BLKS+SCAN1_BLKS){
    int lane=tid&63; int wv=tid>>6;
    {
      int hh=wv;
      float v0 = cg_le[hh*64+lane]*cg_ae[hh*64+lane];
      float v1 = cg_le[256 + hh*64+lane]*cg_ae[hh*64+lane];
      v0=wred_sum(v0); v1=wred_sum(v1);
      if(lane==0){ coefs[8+hh]=v0; coefs[12+hh]=v1; }
    }
    {
      int l=wv>>1, hh=wv&1;
      float v0 = gat_le[l*256 + hh*64+lane]     * gat_ae[l*128+hh*64+lane];
      float v1 = gat_le[l*256 + 128 + hh*64+lane]* gat_ae[l*128+hh*64+lane];
      v0=wred_sum(v0); v1=wred_sum(v1);
      if(lane==0){ coefs[16+l*2+hh]=v0; coefs[20+l*2+hh]=v1; }
    }
    __syncthreads();
    if(wv==0){
      float sx=0.f, sy=0.f;
      for(int i=lane;i<B_FEI;i+=64){ float2 v=partA[i]; sx+=v.x; sy+=v.y; }
      sx=wred_sum(sx); sy=wred_sum(sy);
      if(lane==0){ coefs[4]=sx/(float)E_EDGES; coefs[5]=sy/(float)E_EDGES; }
    }
    if(wv==1){
      float sx=0.f, sy=0.f;
      for(int i=lane;i<B_CEI;i+=64){ float2 v=partB[i]; sx+=v.x; sy+=v.y; }
      sx=wred_sum(sx); sy=wred_sum(sy);
      if(lane==0){ coefs[6]=sx/(float)Ec; coefs[7]=sy/(float)Ec; }
    }
  } else if(b < FUS_BLKS+SCAN1_BLKS+1+B_COPY){
    int i = (b-FUS_BLKS-SCAN1_BLKS-1)*256+tid;
    ((float4*)X)[i] = ((const float4*)u)[i];
  } else {
    __shared__ int hist2[NC];
    int bb = b-(FUS_BLKS+SCAN1_BLKS+1+B_COPY);
    for(int i=tid;i<NC;i+=256) hist2[i]=0;
    __syncthreads();
    for(int n=bb*256+tid; n<NTOT; n+=B_CC*256) atomicAdd(&hist2[ca[n]],1);
    __syncthreads();
    for(int i=tid;i<NC;i+=256) if(hist2[i]) atomicAdd(&ccnt[i],hist2[i]);
  }
}

// ---------------- K4: scan3 (+dinv +self-loop slot) | cluster scan | xw ----------------
__global__ __launch_bounds__(256) void mid_kernel(
    const int* __restrict__ incl, const int* __restrict__ cnt,
    const int* __restrict__ bsum, int* __restrict__ offs, int* __restrict__ fillptr,
    const float* __restrict__ coefs, int2* __restrict__ slot2,
    const int* __restrict__ degI, float* __restrict__ dinv,
    const int* __restrict__ ccnt_dst, int* __restrict__ coffs, int* __restrict__ cfillp,
    const float* __restrict__ X, const float* __restrict__ gw, float* __restrict__ xw)
{
  __shared__ float Wl[64*64];
  __shared__ float rowb[4][64];
  __shared__ int sprev;
  const int b=blockIdx.x, t=threadIdx.x;
  if(b < SC3_BLKS){
    int blk10 = b>>2;
    if(t<64){
      int v = (t<blk10)? bsum[t] : 0;
      v = wred_sumi(v);
      if(t==0) sprev=v;
    }
    __syncthreads();
    unsigned pk = pack_bf2(coefs[4], coefs[5]);
    int i = b*256+t;
    if(i<NTOT){
      int c=cnt[i];
      int start = sprev + incl[i] - (c+1);
      offs[i]=start; fillptr[i]=start;
      slot2[start+c]=make_int2(i,(int)pk);
      dinv[i]=rsqrtf((float)(degI[i]+1));
    }
    if(i==0) offs[NTOT]=E_EDGES+NTOT;
  } else if(b == SC3_BLKS){
    if(t<64){
      int lane=t;
      int v0 = (2*lane<NC)? ccnt_dst[2*lane]:0;
      int v1 = (2*lane+1<NC)? ccnt_dst[2*lane+1]:0;
      int pair=v0+v1;
      int sc=pair;
#pragma unroll
      for(int o=1;o<64;o<<=1){ int t2=__shfl_up(sc,o,64); if(lane>=o) sc+=t2; }
      int excl = sc - pair;
      if(2*lane<NC){ coffs[2*lane]=excl; cfillp[2*lane]=excl; }
      if(2*lane+1<NC){ coffs[2*lane+1]=excl+v0; cfillp[2*lane+1]=excl+v0; }
      if(lane==63) coffs[NC]=sc;
    }
  } else {
    int bb=b-SC3_BLKS-1;
    const int lane=t&63, wv=t>>6;
    for(int i=t;i<4096;i+=256) Wl[i]=gw[i];
    __syncthreads();
    for(int r=bb*4+wv; r<NTOT; r+=1024*4){
      rowb[wv][lane]=X[(size_t)r*64+lane];
      float acc=0.f;
#pragma unroll 8
      for(int k=0;k<64;k++) acc+=rowb[wv][k]*Wl[k*64+lane];
      xw[(size_t)r*64+lane]=acc;
    }
  }
}

// ---------------- K5: fill (full-graph 8B slots | cluster edges) ----------------
__global__ __launch_bounds__(256) void fill_kernel(
    const int* __restrict__ fei, const float* __restrict__ fea,
    int* __restrict__ fillptr, int2* __restrict__ slot2,
    const int* __restrict__ cei, const float* __restrict__ cea, int Ec,
    int* __restrict__ cfillp, int* __restrict__ cslot_src, float2* __restrict__ cslot_ea)
{
  __shared__ int hist[NC];
  __shared__ int base[NC];
  const int b=blockIdx.x, t=threadIdx.x;
  if(b<FILL_BLKS){
    int e=b*256+t;
    if(e<E_EDGES){
      int dst=fei[E_EDGES+e], src=fei[e];
      int pos=atomicAdd(&fillptr[dst],1);
      float2 v=*(const float2*)(fea+2*e);
      slot2[pos]=make_int2(src,(int)pack_bf2(v.x,v.y));
    }
  } else {
    int bb=b-FILL_BLKS;
    const int chunk=(Ec+127)/128;
    const int beg=bb*chunk;
    const int end=min(beg+chunk,Ec);
    for(int i=t;i<NC;i+=256) hist[i]=0;
    __syncthreads();
    for(int e=beg+t;e<end;e+=256) atomicAdd(&hist[cei[Ec+e]],1);
    __syncthreads();
    for(int i=t;i<NC;i+=256){
      int h=hist[i];
      base[i] = h ? atomicAdd(&cfillp[i],h) : 0;
      hist[i]=0;
    }
    __syncthreads();
    for(int e=beg+t;e<end;e+=256){
      int d=cei[Ec+e];
      int pos = base[d] + atomicAdd(&hist[d],1);
      cslot_src[pos]=cei[e];
      cslot_ea[pos]=make_float2(cea[2*e],cea[2*e+1]);
    }
  }
}

// ---------------- K6: persistent tail (normal launch, manual grid barriers) ----------------
// P1 gcn->Xc | P2 cluster_prep | P3 cluster_agg | P4 xh0 (Xc->Xa,xh2,a*) |
// P5 agg0->g,spart0 | P6 xh1 (GN(g)+Xa->Xb,xh2,a*) | P7 agg1->g,spart1 | P8 GN+ELU->out
__global__ __launch_bounds__(256,4) void tail_persist_kernel(
    const float* __restrict__ X, const float* __restrict__ xw, const float* __restrict__ gcn_b,
    const int* __restrict__ offs, const int2* __restrict__ slot2, const int* __restrict__ ca,
    const float* __restrict__ dinv, const int* __restrict__ flag, float* __restrict__ psum,
    const int* __restrict__ ccnt, const float* __restrict__ cg_lin,
    const float* __restrict__ cg_as, const float* __restrict__ cg_ad,
    const int* __restrict__ coffs, const int* __restrict__ cslot_src, const float2* __restrict__ cslot_ea,
    const float* __restrict__ coefs, const float* __restrict__ cg_bias,
    float* __restrict__ xh_c, float* __restrict__ asrc_c, float* __restrict__ adst_c,
    float* __restrict__ cl_upd,
    const float* __restrict__ gat_lin, const float* __restrict__ gat_as, const float* __restrict__ gat_ad,
    const float* __restrict__ gat_bias,
    const float* __restrict__ gn_w, const float* __restrict__ gn_b, const float* __restrict__ gn_ms,
    float* __restrict__ Xc, float* __restrict__ Xa, float* __restrict__ Xb, float* __restrict__ g,
    float2* __restrict__ xh2, float* __restrict__ asrc, float* __restrict__ adst,
    float* __restrict__ spart0, float* __restrict__ spart1,
    int* __restrict__ bflags, int* __restrict__ brel, float* __restrict__ outp)
{
  __shared__ __align__(16) char smraw[35840];
  const int t=threadIdx.x, lane=t&63, wv=t>>6;
  const int wbase = blockIdx.x*4+wv;
  const float invN = 1.f/(float)NTOT;

  // ---- P1: GCN aggregate ----
  {
    float2 (*stg)[64] = (float2(*)[64])smraw;
    for(int n=wbase; n<NTOT; n+=NSTRIDE){
      int beg=offs[n], end=offs[n+1], myca=ca[n];
      float acc=0.f;
      for(int c0=beg;c0<end;c0+=64){
        int j=c0+lane;
        float coef=0.f; int s=0;
        if(j<end){ s=slot2[j].x; if(ca[s]==myca) coef=dinv[s]; }
        stg[wv][lane]=make_float2(__int_as_float(s),coef);
        unsigned long long bal=__ballot(coef!=0.f);
        while(bal){
          int k=__builtin_ctzll(bal); bal&=bal-1;
          float2 sc=stg[wv][k];
          acc += sc.y * xw[(size_t)__float_as_int(sc.x)*64+lane];
        }
      }
      float gout = dinv[n]*acc + gcn_b[lane];
      float xc = flag[myca] ? gout : X[(size_t)n*64+lane];
      Xc[(size_t)n*64+lane]=xc;
      atomicAdd(&psum[(size_t)(blockIdx.x&(PPART-1))*NC*64 + myca*64+lane], xc);
    }
  }
  grid_bar(bflags, brel, 1);

  // ---- P2: cluster_prep (blocks < NC) ----
  if(blockIdx.x < NC){
    float* prow = (float*)smraw;
    const int c=blockIdx.x;
    if(t<64){
      float a=0.f;
#pragma unroll
      for(int p=0;p<PPART;p++) a += psum[(size_t)p*NC*64 + c*64 + t];
      prow[t]=a/fmaxf((float)ccnt[c],1.f);
    }
    __syncthreads();
    float acc=0.f;
#pragma unroll 8
    for(int k=0;k<64;k++) acc += prow[k]*cg_lin[k*256+t];
    xh_c[c*256+t]=acc;
    float s=wred_sum(acc*cg_as[wv*64+lane]);
    float d=wred_sum(acc*cg_ad[wv*64+lane]);
    if(lane==0){ asrc_c[c*4+wv]=s; adst_c[c*4+wv]=d; }
  }
  grid_bar(bflags, brel, 2);

  // ---- P3: cluster_agg (blocks < NC) ----
  if(blockIdx.x < NC){
    float* sas = (float*)smraw;             // 400
    float* sW  = sas+400;                   // 400
    float* ssum= sW+400;                    // 4
    float* red = ssum+4;                    // 256
    const int c=blockIdx.x;
    for(int i=t;i<NC*4;i+=256){ sas[i]=asrc_c[i]; sW[i]=0.f; }
    __syncthreads();
    float ad4[4], A0[4], A1[4];
#pragma unroll
    for(int h=0;h<4;h++){ ad4[h]=adst_c[c*4+h]; A0[h]=coefs[8+h]; A1[h]=coefs[12+h]; }
    const int beg=coffs[c], end=coffs[c+1];
    for(int j=beg+t;j<end;j+=256){
      int s=cslot_src[j]; float2 e=cslot_ea[j];
#pragma unroll
      for(int h=0;h<4;h++){
        float al=lrelu(sas[s*4+h]+ad4[h]+e.x*A0[h]+e.y*A1[h]);
        atomicAdd(&sW[s*4+h], __expf(al));
      }
    }
    if(t<4){
      float al=lrelu(sas[c*4+t]+ad4[t]+coefs[6]*A0[t]+coefs[7]*A1[t]);
      atomicAdd(&sW[c*4+t], __expf(al));
    }
    __syncthreads();
    {
      float p=0.f;
      if(lane<NC)    p += sW[lane*4+wv];
      if(lane+64<NC) p += sW[(lane+64)*4+wv];
      p=wred_sum(p);
      if(lane==0) ssum[wv]=p+1e-16f;
    }
    __syncthreads();
    float inv=1.f/ssum[wv];
    float acc=0.f;
    for(int s=0;s<NC;s++) acc += sW[s*4+wv]*xh_c[s*256+wv*64+lane];
    red[wv*64+lane]=acc*inv;
    __syncthreads();
    if(t<64) cl_upd[c*64+t]=0.25f*(red[t]+red[64+t]+red[128+t]+red[192+t])+cg_bias[t];
  }
  grid_bar(bflags, brel, 3);

  // ---- P4: xh0 ----
  {
    float* Wl = (float*)smraw;                      // 32768 B
    float (*rowb)[64] = (float(*)[64])(smraw+32768);
    for(int i=t;i<8192;i+=256) Wl[i]=gat_lin[i];
    __syncthreads();
    float as0=gat_as[lane], as1=gat_as[64+lane], ad0=gat_ad[lane], ad1=gat_ad[64+lane];
    for(int r=wbase; r<NTOT; r+=NSTRIDE){
      float xv = Xc[(size_t)r*64+lane] + cl_upd[ca[r]*64+lane];
      Xa[(size_t)r*64+lane]=xv;
      rowb[wv][lane]=xv;
      float x0=0.f,x1=0.f;
#pragma unroll 8
      for(int k=0;k<64;k++){ float q=rowb[wv][k]; x0+=q*Wl[k*128+lane]; x1+=q*Wl[k*128+64+lane]; }
      xh2[(size_t)r*64+lane]=make_float2(x0,x1);
      float p0=wred_sum(x0*as0);
      float p1=wred_sum(x1*as1);
      float q0=wred_sum(x0*ad0);
      float q1=wred_sum(x1*ad1);
      if(lane==0){ asrc[2*r]=p0; asrc[2*r+1]=p1; adst[2*r]=q0; adst[2*r+1]=q1; }
    }
  }
  grid_bar(bflags, brel, 4);

  // ---- P5: agg0 -> g, spart0 ----
  {
    float4 (*stg)[64] = (float4(*)[64])smraw;
    float* s1 = (float*)(smraw+4096);
    float* s2 = s1+64;
    if(t<64){ s1[t]=0.f; s2[t]=0.f; }
    __syncthreads();
    float A00=coefs[16], A01=coefs[17], A10=coefs[20], A11=coefs[21];
    for(int n=wbase; n<NTOT; n+=NSTRIDE){
      int beg=offs[n], end=offs[n+1];
      float2 adn=*(const float2*)(adst+2*n);
      float s0=0.f,sB=0.f,acc0=0.f,acc1=0.f;
      for(int c0=beg;c0<end;c0+=64){
        int j=c0+lane;
        float ex0=0.f,ex1=0.f; int s=0;
        if(j<end){
          int2 sl=slot2[j];
          s=sl.x;
          unsigned p=(unsigned)sl.y;
          float e0=__uint_as_float(p<<16);
          float e1=__uint_as_float(p&0xffff0000u);
          float2 a=*(const float2*)(asrc+2*s);
          ex0=__expf(lrelu(a.x+adn.x+e0*A00+e1*A10));
          ex1=__expf(lrelu(a.y+adn.y+e0*A01+e1*A11));
        }
        s0+=ex0; sB+=ex1;
        stg[wv][lane]=make_float4(__int_as_float(s),ex0,ex1,0.f);
        int cnt=min(64,end-c0);
        int k=0;
        for(; k+4<=cnt; k+=4){
          float4 w0=stg[wv][k], w1=stg[wv][k+1], w2=stg[wv][k+2], w3=stg[wv][k+3];
          float2 x0=xh2[(size_t)__float_as_int(w0.x)*64+lane];
          float2 x1=xh2[(size_t)__float_as_int(w1.x)*64+lane];
          float2 x2=xh2[(size_t)__float_as_int(w2.x)*64+lane];
          float2 x3=xh2[(size_t)__float_as_int(w3.x)*64+lane];
          acc0 += w0.y*x0.x + w1.y*x1.x + w2.y*x2.x + w3.y*x3.x;
          acc1 += w0.z*x0.y + w1.z*x1.y + w2.z*x2.y + w3.z*x3.y;
        }
        for(; k<cnt; k++){
          float4 ws=stg[wv][k];
          float2 xv=xh2[(size_t)__float_as_int(ws.x)*64+lane];
          acc0 += ws.y*xv.x;
          acc1 += ws.z*xv.y;
        }
      }
      s0=wred_sum(s0); sB=wred_sum(sB);
      float gv = 0.5f*(acc0/(s0+1e-16f)+acc1/(sB+1e-16f))+gat_bias[lane];
      g[(size_t)n*64+lane]=gv;
      atomicAdd(&s1[lane],gv);
      atomicAdd(&s2[lane],gv*gv);
    }
    __syncthreads();
    float* dstp = spart0 + (size_t)(blockIdx.x&(SPART-1))*128;
    if(t<64) atomicAdd(&dstp[t],s1[t]);
    else if(t<128) atomicAdd(&dstp[t],s2[t-64]);
  }
  grid_bar(bflags, brel, 5);

  // ---- P6: xh1 (GraphNorm(g)+ELU -> Xb; xh2/asrc/adst layer1) ----
  {
    float* Wl = (float*)smraw;
    float (*rowb)[64] = (float(*)[64])(smraw+32768);
    float* smm = (float*)(smraw+33792);
    float* svv = (float*)(smraw+34816);
    for(int i=t;i<8192;i+=256) Wl[i]=gat_lin[8192+i];
    {
      float a0=0.f,a1=0.f;
      for(int p=wv;p<SPART;p+=4){ a0+=spart0[p*128+lane]; a1+=spart0[p*128+64+lane]; }
      smm[wv*64+lane]=a0; svv[wv*64+lane]=a1;
    }
    __syncthreads();
    float m=(smm[lane]+smm[64+lane]+smm[128+lane]+smm[192+lane])*invN;
    float vs=(svv[lane]+svv[64+lane]+svv[128+lane]+svv[192+lane])*invN;
    float mm=gn_ms[lane]*m;
    float gwv=rsqrtf(vs - 2.f*mm*m + mm*mm + 1e-5f)*gn_w[lane];
    float gbv=gn_b[lane];
    float as0=gat_as[128+lane], as1=gat_as[192+lane], ad0=gat_ad[128+lane], ad1=gat_ad[192+lane];
    for(int r=wbase; r<NTOT; r+=NSTRIDE){
      float z=(g[(size_t)r*64+lane]-mm)*gwv+gbv + Xa[(size_t)r*64+lane];
      float xv = z>0.f? z : __expf(z)-1.f;
      Xb[(size_t)r*64+lane]=xv;
      rowb[wv][lane]=xv;
      float x0=0.f,x1=0.f;
#pragma unroll 8
      for(int k=0;k<64;k++){ float q=rowb[wv][k]; x0+=q*Wl[k*128+lane]; x1+=q*Wl[k*128+64+lane]; }
      xh2[(size_t)r*64+lane]=make_float2(x0,x1);
      float p0=wred_sum(x0*as0);
      float p1=wred_sum(x1*as1);
      float q0=wred_sum(x0*ad0);
      float q1=wred_sum(x1*ad1);
      if(lane==0){ asrc[2*r]=p0; asrc[2*r+1]=p1; adst[2*r]=q0; adst[2*r+1]=q1; }
    }
  }
  grid_bar(bflags, brel, 6);

  // ---- P7: agg1 -> g, spart1 ----
  {
    float4 (*stg)[64] = (float4(*)[64])smraw;
    float* s1 = (float*)(smraw+4096);
    float* s2 = s1+64;
    if(t<64){ s1[t]=0.f; s2[t]=0.f; }
    __syncthreads();
    float A00=coefs[18], A01=coefs[19], A10=coefs[22], A11=coefs[23];
    for(int n=wbase; n<NTOT; n+=NSTRIDE){
      int beg=offs[n], end=offs[n+1];
      float2 adn=*(const float2*)(adst+2*n);
      float s0=0.f,sB=0.f,acc0=0.f,acc1=0.f;
      for(int c0=beg;c0<end;c0+=64){
        int j=c0+lane;
        float ex0=0.f,ex1=0.f; int s=0;
        if(j<end){
          int2 sl=slot2[j];
          s=sl.x;
          unsigned p=(unsigned)sl.y;
          float e0=__uint_as_float(p<<16);
          float e1=__uint_as_float(p&0xffff0000u);
          float2 a=*(const float2*)(asrc+2*s);
          ex0=__expf(lrelu(a.x+adn.x+e0*A00+e1*A10));
          ex1=__expf(lrelu(a.y+adn.y+e0*A01+e1*A11));
        }
        s0+=ex0; sB+=ex1;
        stg[wv][lane]=make_float4(__int_as_float(s),ex0,ex1,0.f);
        int cnt=min(64,end-c0);
        int k=0;
        for(; k+4<=cnt; k+=4){
          float4 w0=stg[wv][k], w1=stg[wv][k+1], w2=stg[wv][k+2], w3=stg[wv][k+3];
          float2 x0=xh2[(size_t)__float_as_int(w0.x)*64+lane];
          float2 x1=xh2[(size_t)__float_as_int(w1.x)*64+lane];
          float2 x2=xh2[(size_t)__float_as_int(w2.x)*64+lane];
          float2 x3=xh2[(size_t)__float_as_int(w3.x)*64+lane];
          acc0 += w0.y*x0.x + w1.y*x1.x + w2.y*x2.x + w3.y*x3.x;
          acc1 += w0.z*x0.y + w1.z*x1.y + w2.z*x2.y + w3.z*x3.y;
        }
        for(; k<cnt; k++){
          float4 ws=stg[wv][k];
          float2 xv=xh2[(size_t)__float_as_int(ws.x)*64+lane];
          acc0 += ws.y*xv.x;
          acc1 += ws.z*xv.y;
        }
      }
      s0=wred_sum(s0); sB=wred_sum(sB);
      float gv = 0.5f*(acc0/(s0+1e-16f)+acc1/(sB+1e-16f))+gat_bias[64+lane];
      g[(size_t)n*64+lane]=gv;
      atomicAdd(&s1[lane],gv);
      atomicAdd(&s2[lane],gv*gv);
    }
    __syncthreads();
    float* dstp = spart1 + (size_t)(blockIdx.x&(SPART-1))*128;
    if(t<64) atomicAdd(&dstp[t],s1[t]);
    else if(t<128) atomicAdd(&dstp[t],s2[t-64]);
  }
  grid_bar(bflags, brel, 7);

  // ---- P8: final GraphNorm+ELU -> out ----
  {
    float* sst = (float*)smraw;   // [2][128]
    {
      int d=t&127, hf=t>>7;
      float a=0.f;
      for(int p=hf*64;p<hf*64+64;p++) a+=spart1[p*128+d];
      sst[hf*128+d]=a;
    }
    __syncthreads();
    float m=(sst[lane]+sst[128+lane])*invN;
    float vs=(sst[64+lane]+sst[192+lane])*invN;
    float mm=gn_ms[64+lane]*m;
    float gwv=rsqrtf(vs - 2.f*mm*m + mm*mm + 1e-5f)*gn_w[64+lane];
    float gbv=gn_b[64+lane];
    for(int n=wbase; n<NTOT; n+=NSTRIDE){
      float z=(g[(size_t)n*64+lane]-mm)*gwv+gbv + Xb[(size_t)n*64+lane];
      outp[(size_t)n*64+lane] = z>0.f? z : __expf(z)-1.f;
    }
  }
}

// ---------------- launch ----------------
extern "C" void kernel_launch(void* const* d_in, const int* in_sizes, int n_in,
                              void* d_out, int out_size, void* d_ws, size_t ws_size,
                              hipStream_t stream)
{
  const float* extra = (const float*)d_in[0];
  const float* user  = (const float*)d_in[1];
  const float* item  = (const float*)d_in[2];
  const float* fw1 = (const float*)d_in[3];
  const float* fb1 = (const float*)d_in[4];
  const float* fw2 = (const float*)d_in[5];
  const float* fb2 = (const float*)d_in[6];
  const float* fea = (const float*)d_in[7];
  const float* gcn_w = (const float*)d_in[8];
  const float* gcn_b = (const float*)d_in[9];
  const float* cg_lin = (const float*)d_in[10];
  const float* cg_as = (const float*)d_in[11];
  const float* cg_ad = (const float*)d_in[12];
  const float* cg_le = (const float*)d_in[13];
  const float* cg_ae = (const float*)d_in[14];
  const float* cg_bias = (const float*)d_in[15];
  const float* cea = (const float*)d_in[16];
  const float* gat_lin = (const float*)d_in[17];
  const float* gat_as = (const float*)d_in[18];
  const float* gat_ad = (const float*)d_in[19];
  const float* gat_le = (const float*)d_in[20];
  const float* gat_ae = (const float*)d_in[21];
  const float* gat_bias = (const float*)d_in[22];
  const float* gn_w = (const float*)d_in[23];
  const float* gn_b = (const float*)d_in[24];
  const float* gn_ms = (const float*)d_in[25];
  const int* fei = (const int*)d_in[26];
  const int* ca  = (const int*)d_in[27];
  const int* cei = (const int*)d_in[28];
  const int Ec = in_sizes[16]/2;
  float* outp = (float*)d_out;

  char* w = (char*)d_ws;
  auto alloc=[&](size_t b)->char*{ char* p=w; w += (b+255)&~(size_t)255; return p; };

  // zero region (single memset)
  char* z0 = w;
  int* cnt_dst = (int*)alloc((size_t)NTOT*4);
  int* degI = (int*)alloc((size_t)NTOT*4);
  int* clflag = (int*)alloc(NC*4);
  int* ccnt = (int*)alloc(NC*4);
  int* ccnt_dst = (int*)alloc(NC*4);
  float* psum = (float*)alloc((size_t)PPART*NC*64*4);
  float* spart0 = (float*)alloc((size_t)SPART*128*4);
  float* spart1 = (float*)alloc((size_t)SPART*128*4);
  int* bflags = (int*)alloc((size_t)GRID_C*4);
  int* brel = (int*)alloc(256);
  size_t zbytes = (size_t)(w - z0);

  float2* partA = (float2*)alloc(2048*8);
  float2* partB = (float2*)alloc(256*8);
  float* coefs = (float*)alloc(32*4);
  int* offs = (int*)alloc((size_t)(NTOT+1)*4);
  int* incl = (int*)alloc((size_t)NTOT*4);
  int* bsum = (int*)alloc(64*4);
  int* fillptr = (int*)alloc((size_t)NTOT*4);
  int2* slot2 = (int2*)alloc((size_t)(E_EDGES+NTOT)*8);
  int* coffs = (int*)alloc((size_t)(NC+1)*4);
  int* cfillp = (int*)alloc((size_t)NC*4);
  int* cslot_src = (int*)alloc((size_t)E_EDGES*4);
  float2* cslot_ea = (float2*)alloc((size_t)E_EDGES*8);
  float* dinv = (float*)alloc((size_t)NTOT*4);
  float* xh_c = (float*)alloc(NC*256*4);
  float* asrc_c = (float*)alloc(NC*4*4);
  float* adst_c = (float*)alloc(NC*4*4);
  float* cl_upd = (float*)alloc(NC*64*4);
  float* asrc = (float*)alloc((size_t)NTOT*2*4);
  float* adst = (float*)alloc((size_t)NTOT*2*4);
  short* w1t = (short*)alloc((size_t)KSTEPS*4096*2);
  short* w2t = (short*)alloc((size_t)64*128*2);
  float* bufA = (float*)alloc((size_t)NTOT*64*4);   // X, then g
  float* bufB = (float*)alloc((size_t)NTOT*64*4);   // Xc, then Xb
  float* bufC = (float*)alloc((size_t)NTOT*64*4);   // xw, then Xa
  float* bufE = (float*)alloc((size_t)NTOT*128*4);  // xh2 (both layers)

  float* X  = bufA; float* g  = bufA;
  float* Xc = bufB; float* Xb = bufB;
  float* xw = bufC; float* Xa = bufC;
  float2* xh2 = (float2*)bufE;

  hipMemsetAsync(z0, 0, zbytes, stream);

  prep_edges_kernel<<<PREP_GRID,256,0,stream>>>(fw1, w1t, fw2, w2t, ca,
                                              fei, fea, cnt_dst, clflag, degI, partA,
                                              cei, cea, Ec, ccnt_dst, partB);
  fus_scan_kernel<<<FUS_GRID,256,0,stream>>>(item, extra, w1t, fb1, w2t, fb2, X,
                                              partA, partB, Ec, cg_le, cg_ae, gat_le, gat_ae, coefs,
                                              cnt_dst, incl, bsum, user, ca, ccnt);
  mid_kernel<<<SC3_BLKS+1+1024,256,0,stream>>>(incl, cnt_dst, bsum, offs, fillptr, coefs, slot2,
                                              degI, dinv, ccnt_dst, coffs, cfillp,
                                              X, gcn_w, xw);
  fill_kernel<<<FILL_BLKS+128,256,0,stream>>>(fei, fea, fillptr, slot2,
                                              cei, cea, Ec, cfillp, cslot_src, cslot_ea);

  tail_persist_kernel<<<GRID_C,256,0,stream>>>(X, xw, gcn_b,
                                              offs, slot2, ca, dinv, clflag, psum,
                                              ccnt, cg_lin, cg_as, cg_ad,
                                              coffs, cslot_src, cslot_ea, coefs, cg_bias,
                                              xh_c, asrc_c, adst_c, cl_upd,
                                              gat_lin, gat_as, gat_ad, gat_bias,
                                              gn_w, gn_b, gn_ms,
                                              Xc, Xa, Xb, g,
                                              xh2, asrc, adst, spart0, spart1,
                                              bflags, brel, outp);
}

// Round 9
// 684.762 us; speedup vs baseline: 2.9928x; 2.9928x over previous
//
#include <hip/hip_runtime.h>
#include <hip/hip_bf16.h>

#define N_USERS 20000
#define N_ITEMS 30000
#define NTOT    50000
#define DIM     64
#define EXTRA_D 1152
#define E_EDGES 500000
#define NC      100
#define KTOT    1216
#define KSTEPS  38
#define PPART   16
#define SPART   128

// prep_edges block ranges
#define B_FEI  1954
#define B_W1   608
#define B_W2   32
#define B_CEI  256
#define PREP_GRID (B_FEI+B_W1+B_W2+B_CEI)   // 2850

// fus_scan block ranges
#define FUS_BLKS ((N_ITEMS+127)/128)     // 235
#define SCAN1_BLKS ((NTOT+1023)/1024)    // 49
#define B_COPY 1250
#define B_CC   64
#define FUS_GRID (FUS_BLKS+SCAN1_BLKS+1+B_COPY+B_CC)  // 1599

#define SC3_BLKS ((NTOT+255)/256)        // 196
#define FILL_BLKS ((E_EDGES+255)/256)    // 1954
#define DEG_BLKS ((NTOT+3)/4)            // 12500 (x4 waves == NTOT exactly)

typedef __attribute__((ext_vector_type(8))) short short8;
typedef __attribute__((ext_vector_type(4))) float v4f;

// ---------------- helpers ----------------
__device__ __forceinline__ float wred_sum(float v){
#pragma unroll
  for(int o=32;o;o>>=1) v += __shfl_xor(v,o,64);
  return v;
}
__device__ __forceinline__ int wred_sumi(int v){
#pragma unroll
  for(int o=32;o;o>>=1) v += __shfl_xor(v,o,64);
  return v;
}
__device__ __forceinline__ float lrelu(float x){ return x>0.f? x : 0.2f*x; }
__device__ __forceinline__ short f2bf(float f){
  unsigned u=__float_as_uint(f);
  unsigned r=(u + 0x7FFFu + ((u>>16)&1u))>>16;
  return (short)r;
}
__device__ __forceinline__ unsigned pack_bf2(float x, float y){
  return (unsigned)(unsigned short)f2bf(x) | ((unsigned)(unsigned short)f2bf(y)<<16);
}

// ---------------- K2: prep_edges ----------------
__global__ __launch_bounds__(256) void prep_edges_kernel(
    const float* __restrict__ w1, short* __restrict__ w1t,
    const float* __restrict__ w2, short* __restrict__ w2t,
    const int* __restrict__ ca,
    const int* __restrict__ fei, const float* __restrict__ fea,
    int* __restrict__ cnt_dst, int* __restrict__ clflag, int* __restrict__ degI,
    float2* __restrict__ partA,
    const int* __restrict__ cei, const float* __restrict__ cea, int Ec,
    int* __restrict__ ccnt_dst, float2* __restrict__ partB)
{
  __shared__ int hist[NC];
  __shared__ float2 w4[4];
  const int b=blockIdx.x, t=threadIdx.x;
  const int lane=t&63, wv=t>>6;
  if(b < B_FEI){
    int e = b*256+t;
    float a0=0.f,a1=0.f;
    if(e<E_EDGES){
      int s=fei[e], d=fei[E_EDGES+e];
      atomicAdd(&cnt_dst[d],1);
      int cs=ca[s];
      if(cs==ca[d]){ clflag[cs]=1; atomicAdd(&degI[d],1); }
      float2 v=*(const float2*)(fea+2*e);
      a0=v.x; a1=v.y;
    }
    a0=wred_sum(a0); a1=wred_sum(a1);
    if(lane==0) w4[wv]=make_float2(a0,a1);
    __syncthreads();
    if(t==0){ float2 r=w4[0]; for(int i=1;i<4;i++){r.x+=w4[i].x; r.y+=w4[i].y;} partA[b]=r; }
  } else if(b < B_FEI+B_W1){
    int i = (b-B_FEI)*256+t;               // 608*256 == 1216*128 exactly
    int row = i>>7, n = i&127;             // coalesced read w1[i]
    int s = row>>5, kk = row&31;
    w1t[s*4096 + n*32 + kk] = f2bf(w1[i]);
  } else if(b < B_FEI+B_W1+B_W2){
    int i = (b-B_FEI-B_W1)*256+t;          // 32*256 == 8192 exactly
    int n = i>>6, c = i&63;                // coalesced read w2[i]
    w2t[c*128 + n] = f2bf(w2[i]);
  } else {
    int bb = b-(B_FEI+B_W1+B_W2);
    for(int i=t;i<NC;i+=256) hist[i]=0;
    __syncthreads();
    float a0=0.f,a1=0.f;
    for(int e=bb*256+t; e<Ec; e+=B_CEI*256){
      atomicAdd(&hist[cei[Ec+e]],1);
      float2 v=*(const float2*)(cea+2*e);
      a0+=v.x; a1+=v.y;
    }
    a0=wred_sum(a0); a1=wred_sum(a1);
    if(lane==0) w4[wv]=make_float2(a0,a1);
    __syncthreads();
    if(t==0){ float2 r=w4[0]; for(int i=1;i<4;i++){r.x+=w4[i].x; r.y+=w4[i].y;} partB[bb]=r; }
    for(int i=t;i<NC;i+=256) if(hist[i]) atomicAdd(&ccnt_dst[i],hist[i]);
  }
}

// ---------------- K3: fusion MFMA | scan1 | prep_small | user copy | ccnt ----------------
__global__ __launch_bounds__(256) void fus_scan_kernel(
    const float* __restrict__ item, const float* __restrict__ extra,
    const short* __restrict__ w1t, const float* __restrict__ b1,
    const short* __restrict__ w2t, const float* __restrict__ b2,
    float* __restrict__ X,
    const float2* __restrict__ partA, const float2* __restrict__ partB, int Ec,
    const float* __restrict__ cg_le, const float* __restrict__ cg_ae,
    const float* __restrict__ gat_le, const float* __restrict__ gat_ae,
    float* __restrict__ coefs,
    const int* __restrict__ cnt_dst, int* __restrict__ incl, int* __restrict__ bsum,
    const float* __restrict__ u, const int* __restrict__ ca, int* __restrict__ ccnt)
{
  __shared__ short As[128*40];
  __shared__ short Bs[128*40];
  __shared__ short Hs[128*136];
  __shared__ int ssc[256];
  const int tid = threadIdx.x;
  const int b = blockIdx.x;
  if(b < FUS_BLKS){
    const int blk = b;
    const int w = tid>>6, lane = tid&63, quad = lane>>4, l16 = lane&15;
    const int mw = w&1, nw = w>>1;

    v4f acc[4][4];
#pragma unroll
    for(int a=0;a<4;a++)
#pragma unroll
      for(int c=0;c<4;c++) acc[a][c] = (v4f){0.f,0.f,0.f,0.f};

    const int arow = tid>>3;
    const int aoff = (tid&7)*4;
    for(int s=0;s<KSTEPS;s++){
      const int k0 = s*32;
#pragma unroll
      for(int it=0;it<4;it++){
        int r = arow + it*32;
        int col = k0 + aoff;
        int gr = blk*128 + r; if(gr >= N_ITEMS) gr = N_ITEMS-1;
        float4 v = (col < DIM) ? *(const float4*)(item + (size_t)gr*DIM + col)
                               : *(const float4*)(extra + (size_t)gr*EXTRA_D + (col-DIM));
        short4 bv; bv.x=f2bf(v.x); bv.y=f2bf(v.y); bv.z=f2bf(v.z); bv.w=f2bf(v.w);
        *(short4*)&As[r*40 + aoff] = bv;
      }
#pragma unroll
      for(int it=0;it<2;it++){
        int idx = tid + it*256;
        int4 v = *(const int4*)(w1t + (size_t)s*4096 + idx*8);
        int n = idx>>2, kk = (idx&3)*8;
        *(int4*)&Bs[n*40 + kk] = v;
      }
      __syncthreads();
      short8 af[4], bf_[4];
#pragma unroll
      for(int i=0;i<4;i++){
        int m = mw*64 + i*16 + l16;
        af[i]  = *(const short8*)&As[m*40 + quad*8];
        int n = nw*64 + i*16 + l16;
        bf_[i] = *(const short8*)&Bs[n*40 + quad*8];
      }
#pragma unroll
      for(int mi=0;mi<4;mi++)
#pragma unroll
        for(int ni=0;ni<4;ni++)
          acc[mi][ni] = __builtin_amdgcn_mfma_f32_16x16x32_bf16(af[mi], bf_[ni], acc[mi][ni], 0,0,0);
      __syncthreads();
    }

#pragma unroll
    for(int ni=0;ni<4;ni++){
      int n = nw*64 + ni*16 + l16;
      float bias = b1[n];
#pragma unroll
      for(int mi=0;mi<4;mi++){
        int mbase = mw*64 + mi*16 + quad*4;
#pragma unroll
        for(int r=0;r<4;r++){
          float hv = fmaxf(acc[mi][ni][r] + bias, 0.f);
          Hs[(mbase+r)*136 + n] = f2bf(hv);
        }
      }
    }
    __syncthreads();

    v4f acc2[2][4];
#pragma unroll
    for(int a=0;a<2;a++)
#pragma unroll
      for(int c=0;c<4;c++) acc2[a][c] = (v4f){0.f,0.f,0.f,0.f};
#pragma unroll
    for(int ks=0;ks<4;ks++){
      short8 ha[2];
#pragma unroll
      for(int mi=0;mi<2;mi++){
        int m = w*32 + mi*16 + l16;
        ha[mi] = *(const short8*)&Hs[m*136 + ks*32 + quad*8];
      }
#pragma unroll
      for(int ni=0;ni<4;ni++){
        int c = ni*16 + l16;
        short8 wb = *(const short8*)(w2t + c*128 + ks*32 + quad*8);
#pragma unroll
        for(int mi=0;mi<2;mi++)
          acc2[mi][ni] = __builtin_amdgcn_mfma_f32_16x16x32_bf16(ha[mi], wb, acc2[mi][ni], 0,0,0);
      }
    }
#pragma unroll
    for(int ni=0;ni<4;ni++){
      int c = ni*16 + l16;
      float b2v = b2[c];
#pragma unroll
      for(int mi=0;mi<2;mi++){
        int mbase = w*32 + mi*16 + quad*4;
#pragma unroll
        for(int r=0;r<4;r++){
          int row = blk*128 + mbase + r;
          if(row < N_ITEMS) X[(size_t)(N_USERS+row)*64 + c] = acc2[mi][ni][r] + b2v;
        }
      }
    }
  } else if(b < FUS_BLKS+SCAN1_BLKS){
    int sb = b-FUS_BLKS;
    int base = sb*1024 + tid*4;
    int a0=(base  <NTOT)?cnt_dst[base  ]+1:0;
    int a1=(base+1<NTOT)?cnt_dst[base+1]+1:0;
    int a2=(base+2<NTOT)?cnt_dst[base+2]+1:0;
    int a3=(base+3<NTOT)?cnt_dst[base+3]+1:0;
    int l1=a0+a1, l2=l1+a2, l3=l2+a3;
    ssc[tid]=l3; __syncthreads();
    for(int off=1;off<256;off<<=1){
      int v=(tid>=off)?ssc[tid-off]:0; __syncthreads();
      ssc[tid]+=v; __syncthreads();
    }
    int prev = tid? ssc[tid-1]:0;
    if(base  <NTOT) incl[base  ]=prev+a0;
    if(base+1<NTOT) incl[base+1]=prev+l1;
    if(base+2<NTOT) incl[base+2]=prev+l2;
    if(base+3<NTOT) incl[base+3]=prev+l3;
    if(tid==255) bsum[sb]=ssc[255];
  } else if(b == FUS_BLKS+SCAN1_BLKS){
    int lane=tid&63; int wv=tid>>6;
    {
      int hh=wv;
      float v0 = cg_le[hh*64+lane]*cg_ae[hh*64+lane];
      float v1 = cg_le[256 + hh*64+lane]*cg_ae[hh*64+lane];
      v0=wred_sum(v0); v1=wred_sum(v1);
      if(lane==0){ coefs[8+hh]=v0; coefs[12+hh]=v1; }
    }
    {
      int l=wv>>1, hh=wv&1;
      float v0 = gat_le[l*256 + hh*64+lane]     * gat_ae[l*128+hh*64+lane];
      float v1 = gat_le[l*256 + 128 + hh*64+lane]* gat_ae[l*128+hh*64+lane];
      v0=wred_sum(v0); v1=wred_sum(v1);
      if(lane==0){ coefs[16+l*2+hh]=v0; coefs[20+l*2+hh]=v1; }
    }
    __syncthreads();
    if(wv==0){
      float sx=0.f, sy=0.f;
      for(int i=lane;i<B_FEI;i+=64){ float2 v=partA[i]; sx+=v.x; sy+=v.y; }
      sx=wred_sum(sx); sy=wred_sum(sy);
      if(lane==0){ coefs[4]=sx/(float)E_EDGES; coefs[5]=sy/(float)E_EDGES; }
    }
    if(wv==1){
      float sx=0.f, sy=0.f;
      for(int i=lane;i<B_CEI;i+=64){ float2 v=partB[i]; sx+=v.x; sy+=v.y; }
      sx=wred_sum(sx); sy=wred_sum(sy);
      if(lane==0){ coefs[6]=sx/(float)Ec; coefs[7]=sy/(float)Ec; }
    }
  } else if(b < FUS_BLKS+SCAN1_BLKS+1+B_COPY){
    int i = (b-FUS_BLKS-SCAN1_BLKS-1)*256+tid;
    ((float4*)X)[i] = ((const float4*)u)[i];
  } else {
    __shared__ int hist2[NC];
    int bb = b-(FUS_BLKS+SCAN1_BLKS+1+B_COPY);
    for(int i=tid;i<NC;i+=256) hist2[i]=0;
    __syncthreads();
    for(int n=bb*256+tid; n<NTOT; n+=B_CC*256) atomicAdd(&hist2[ca[n]],1);
    __syncthreads();
    for(int i=tid;i<NC;i+=256) if(hist2[i]) atomicAdd(&ccnt[i],hist2[i]);
  }
}

// ---------------- K4: scan3 (+dinv +self-loop slot) | cluster scan | xw ----------------
__global__ __launch_bounds__(256) void mid_kernel(
    const int* __restrict__ incl, const int* __restrict__ cnt,
    const int* __restrict__ bsum, int* __restrict__ offs, int* __restrict__ fillptr,
    const float* __restrict__ coefs, int2* __restrict__ slot2,
    const int* __restrict__ degI, float* __restrict__ dinv,
    const int* __restrict__ ccnt_dst, int* __restrict__ coffs, int* __restrict__ cfillp,
    const float* __restrict__ X, const float* __restrict__ gw, float* __restrict__ xw)
{
  __shared__ float Wl[64*64];
  __shared__ float rowb[4][64];
  __shared__ int sprev;
  const int b=blockIdx.x, t=threadIdx.x;
  if(b < SC3_BLKS){
    int blk10 = b>>2;
    if(t<64){
      int v = (t<blk10)? bsum[t] : 0;
      v = wred_sumi(v);
      if(t==0) sprev=v;
    }
    __syncthreads();
    unsigned pk = pack_bf2(coefs[4], coefs[5]);
    int i = b*256+t;
    if(i<NTOT){
      int c=cnt[i];
      int start = sprev + incl[i] - (c+1);
      offs[i]=start; fillptr[i]=start;
      slot2[start+c]=make_int2(i,(int)pk);
      dinv[i]=rsqrtf((float)(degI[i]+1));
    }
    if(i==0) offs[NTOT]=E_EDGES+NTOT;
  } else if(b == SC3_BLKS){
    if(t<64){
      int lane=t;
      int v0 = (2*lane<NC)? ccnt_dst[2*lane]:0;
      int v1 = (2*lane+1<NC)? ccnt_dst[2*lane+1]:0;
      int pair=v0+v1;
      int sc=pair;
#pragma unroll
      for(int o=1;o<64;o<<=1){ int t2=__shfl_up(sc,o,64); if(lane>=o) sc+=t2; }
      int excl = sc - pair;
      if(2*lane<NC){ coffs[2*lane]=excl; cfillp[2*lane]=excl; }
      if(2*lane+1<NC){ coffs[2*lane+1]=excl+v0; cfillp[2*lane+1]=excl+v0; }
      if(lane==63) coffs[NC]=sc;
    }
  } else {
    int bb=b-SC3_BLKS-1;
    const int lane=t&63, wv=t>>6;
    for(int i=t;i<4096;i+=256) Wl[i]=gw[i];
    __syncthreads();
    for(int r=bb*4+wv; r<NTOT; r+=1024*4){
      rowb[wv][lane]=X[(size_t)r*64+lane];
      float acc=0.f;
#pragma unroll 8
      for(int k=0;k<64;k++) acc+=rowb[wv][k]*Wl[k*64+lane];
      xw[(size_t)r*64+lane]=acc;
    }
  }
}

// ---------------- K5: fill (full-graph 8B slots | cluster edges) ----------------
__global__ __launch_bounds__(256) void fill_kernel(
    const int* __restrict__ fei, const float* __restrict__ fea,
    int* __restrict__ fillptr, int2* __restrict__ slot2,
    const int* __restrict__ cei, const float* __restrict__ cea, int Ec,
    int* __restrict__ cfillp, int* __restrict__ cslot_src, float2* __restrict__ cslot_ea)
{
  __shared__ int hist[NC];
  __shared__ int base[NC];
  const int b=blockIdx.x, t=threadIdx.x;
  if(b<FILL_BLKS){
    int e=b*256+t;
    if(e<E_EDGES){
      int dst=fei[E_EDGES+e], src=fei[e];
      int pos=atomicAdd(&fillptr[dst],1);
      float2 v=*(const float2*)(fea+2*e);
      slot2[pos]=make_int2(src,(int)pack_bf2(v.x,v.y));
    }
  } else {
    int bb=b-FILL_BLKS;
    const int chunk=(Ec+127)/128;
    const int beg=bb*chunk;
    const int end=min(beg+chunk,Ec);
    for(int i=t;i<NC;i+=256) hist[i]=0;
    __syncthreads();
    for(int e=beg+t;e<end;e+=256) atomicAdd(&hist[cei[Ec+e]],1);
    __syncthreads();
    for(int i=t;i<NC;i+=256){
      int h=hist[i];
      base[i] = h ? atomicAdd(&cfillp[i],h) : 0;
      hist[i]=0;
    }
    __syncthreads();
    for(int e=beg+t;e<end;e+=256){
      int d=cei[Ec+e];
      int pos = base[d] + atomicAdd(&hist[d],1);
      cslot_src[pos]=cei[e];
      cslot_ea[pos]=make_float2(cea[2*e],cea[2*e+1]);
    }
  }
}

// ---------------- K6: GCN aggregate (ballot-sparse) ----------------
__global__ __launch_bounds__(256) void gcn_agg_kernel(const float* __restrict__ X,
    const float* __restrict__ xw, const float* __restrict__ gcn_b,
    const int* __restrict__ offs, const int2* __restrict__ slot2, const int* __restrict__ ca,
    const float* __restrict__ dinv, const int* __restrict__ flag,
    float* __restrict__ Xc, float* __restrict__ psum){
  __shared__ float2 stg[4][64];
  int lane=threadIdx.x&63, wv=threadIdx.x>>6;
  int n=blockIdx.x*4+wv;
  int beg=offs[n], end=offs[n+1], myca=ca[n];
  float acc=0.f;
  for(int c0=beg;c0<end;c0+=64){
    int j=c0+lane;
    float coef=0.f; int s=0;
    if(j<end){
      s=slot2[j].x;
      if(ca[s]==myca) coef=dinv[s];
    }
    stg[wv][lane]=make_float2(__int_as_float(s),coef);
    unsigned long long bal=__ballot(coef!=0.f);
    while(bal){
      int k=__builtin_ctzll(bal); bal&=bal-1;
      float2 sc=stg[wv][k];
      acc += sc.y * xw[(size_t)__float_as_int(sc.x)*64+lane];
    }
  }
  float gout = dinv[n]*acc + gcn_b[lane];
  float xc = flag[myca] ? gout : X[(size_t)n*64+lane];
  Xc[(size_t)n*64+lane]=xc;
  atomicAdd(&psum[(size_t)(blockIdx.x&(PPART-1))*NC*64 + myca*64+lane], xc);
}

// ---------------- K7: cluster prep (pooled + xh_c + att) ----------------
__global__ __launch_bounds__(256) void cluster_prep_kernel(const float* __restrict__ psum,
    const int* __restrict__ ccnt, const float* __restrict__ cg_lin,
    const float* __restrict__ as_, const float* __restrict__ ad_,
    float* __restrict__ xh_c, float* __restrict__ asrc_c, float* __restrict__ adst_c){
  __shared__ float prow[64];
  const int c=blockIdx.x, t=threadIdx.x;
  if(t<64){
    float a=0.f;
#pragma unroll
    for(int p=0;p<PPART;p++) a += psum[(size_t)p*NC*64 + c*64 + t];
    prow[t]=a/fmaxf((float)ccnt[c],1.f);
  }
  __syncthreads();
  float acc=0.f;
#pragma unroll 8
  for(int k=0;k<64;k++) acc += prow[k]*cg_lin[k*256+t];
  xh_c[c*256+t]=acc;
  int lane=t&63, hh=t>>6;
  float s=wred_sum(acc*as_[hh*64+lane]);
  float d=wred_sum(acc*ad_[hh*64+lane]);
  if(lane==0){ asrc_c[c*4+hh]=s; adst_c[c*4+hh]=d; }
}
// ---------------- K8: cluster GAT aggregate ----------------
__global__ __launch_bounds__(256) void cluster_agg_kernel(
    const int* __restrict__ coffs, const int* __restrict__ cslot_src, const float2* __restrict__ cslot_ea,
    const float* __restrict__ asrc_c, const float* __restrict__ adst_c, const float* __restrict__ coefs,
    const float* __restrict__ xh_c, const float* __restrict__ cg_bias, float* __restrict__ cl_upd)
{
  __shared__ float sas[NC*4];
  __shared__ float sW[NC*4];
  __shared__ float ssum[4];
  __shared__ float red[4][64];
  const int c=blockIdx.x, t=threadIdx.x;
  for(int i=t;i<NC*4;i+=256){ sas[i]=asrc_c[i]; sW[i]=0.f; }
  __syncthreads();
  float ad[4], A0[4], A1[4];
#pragma unroll
  for(int h=0;h<4;h++){ ad[h]=adst_c[c*4+h]; A0[h]=coefs[8+h]; A1[h]=coefs[12+h]; }
  const int beg=coffs[c], end=coffs[c+1];
  for(int j=beg+t;j<end;j+=256){
    int s=cslot_src[j]; float2 e=cslot_ea[j];
#pragma unroll
    for(int h=0;h<4;h++){
      float al=lrelu(sas[s*4+h]+ad[h]+e.x*A0[h]+e.y*A1[h]);
      atomicAdd(&sW[s*4+h], __expf(al));
    }
  }
  if(t<4){
    float al=lrelu(sas[c*4+t]+ad[t]+coefs[6]*A0[t]+coefs[7]*A1[t]);
    atomicAdd(&sW[c*4+t], __expf(al));
  }
  __syncthreads();
  const int h=t>>6, lane=t&63;
  float p=0.f;
  if(lane<NC)    p += sW[lane*4+h];
  if(lane+64<NC) p += sW[(lane+64)*4+h];
  p=wred_sum(p);
  if(lane==0) ssum[h]=p+1e-16f;
  __syncthreads();
  float inv=1.f/ssum[h];
  float acc=0.f;
  for(int s=0;s<NC;s++) acc += sW[s*4+h]*xh_c[s*256+h*64+lane];
  red[h][lane]=acc*inv;
  __syncthreads();
  if(t<64) cl_upd[c*64+t]=0.25f*(red[0][t]+red[1][t]+red[2][t]+red[3][t])+cg_bias[t];
}

// ---------------- K9: GAT layer 0 xh (fused xcomb; xh2 packed bf16x2) ----------------
__global__ __launch_bounds__(256) void gat_xh0_kernel(const float* __restrict__ Xc,
    const float* __restrict__ cl_upd, const int* __restrict__ ca,
    const float* __restrict__ lin, const float* __restrict__ att_s, const float* __restrict__ att_d,
    unsigned* __restrict__ xh2p, float* __restrict__ asrc, float* __restrict__ adst,
    float* __restrict__ Xa){
  __shared__ __align__(16) float Wl[64*128];
  __shared__ float rowb[4][64];
  int t=threadIdx.x;
  for(int i=t;i<8192;i+=256) Wl[i]=lin[i];
  __syncthreads();
  int lane=t&63, wv=t>>6;
  float as0=att_s[lane], as1=att_s[64+lane], ad0=att_d[lane], ad1=att_d[64+lane];
  for(int r=blockIdx.x*4+wv; r<NTOT; r+=gridDim.x*4){
    float xv = Xc[(size_t)r*64+lane] + cl_upd[ca[r]*64+lane];
    Xa[(size_t)r*64+lane]=xv;
    rowb[wv][lane]=xv;
    float x0=0.f,x1=0.f;
#pragma unroll 8
    for(int k=0;k<64;k++){ float q=rowb[wv][k]; x0+=q*Wl[k*128+lane]; x1+=q*Wl[k*128+64+lane]; }
    xh2p[(size_t)r*64+lane]=pack_bf2(x0,x1);
    float p0=wred_sum(x0*as0);
    float p1=wred_sum(x1*as1);
    float q0=wred_sum(x0*ad0);
    float q1=wred_sum(x1*ad1);
    if(lane==0){ asrc[2*r]=p0; asrc[2*r+1]=p1; adst[2*r]=q0; adst[2*r+1]=q1; }
  }
}
// ---------------- K11: GAT layer 1 xh (fused GraphNorm+ELU, spart-reduce; xh2 packed) ----------------
__global__ __launch_bounds__(256) void gat_xh1_kernel(const float* __restrict__ g,
    const float* __restrict__ Xres, const float* __restrict__ spart,
    const float* __restrict__ gnw, const float* __restrict__ gnb, const float* __restrict__ gnms,
    const float* __restrict__ lin, const float* __restrict__ att_s, const float* __restrict__ att_d,
    unsigned* __restrict__ xh2p, float* __restrict__ asrc, float* __restrict__ adst,
    float* __restrict__ Xb){
  __shared__ __align__(16) float Wl[64*128];
  __shared__ float rowb[4][64];
  __shared__ float sm[4][64], sv[4][64];
  int t=threadIdx.x;
  int lane=t&63, wv=t>>6;
  for(int i=t;i<8192;i+=256) Wl[i]=lin[i];
  {
    float a0=0.f,a1=0.f;
    for(int p=wv;p<SPART;p+=4){ a0+=spart[p*128+lane]; a1+=spart[p*128+64+lane]; }
    sm[wv][lane]=a0; sv[wv][lane]=a1;
  }
  __syncthreads();
  const float invN = 1.f/(float)NTOT;
  float m=(sm[0][lane]+sm[1][lane]+sm[2][lane]+sm[3][lane])*invN;
  float vsum=(sv[0][lane]+sv[1][lane]+sv[2][lane]+sv[3][lane])*invN;
  float mm=gnms[lane]*m;
  float gwv=rsqrtf(vsum - 2.f*mm*m + mm*mm + 1e-5f)*gnw[lane];
  float gbv=gnb[lane];
  float as0=att_s[lane], as1=att_s[64+lane], ad0=att_d[lane], ad1=att_d[64+lane];
  for(int r=blockIdx.x*4+wv; r<NTOT; r+=gridDim.x*4){
    float z=(g[(size_t)r*64+lane]-mm)*gwv+gbv + Xres[(size_t)r*64+lane];
    float xv = z>0.f? z : __expf(z)-1.f;
    Xb[(size_t)r*64+lane]=xv;
    rowb[wv][lane]=xv;
    float x0=0.f,x1=0.f;
#pragma unroll 8
    for(int k=0;k<64;k++){ float q=rowb[wv][k]; x0+=q*Wl[k*128+lane]; x1+=q*Wl[k*128+64+lane]; }
    xh2p[(size_t)r*64+lane]=pack_bf2(x0,x1);
    float p0=wred_sum(x0*as0);
    float p1=wred_sum(x1*as1);
    float q0=wred_sum(x0*ad0);
    float q1=wred_sum(x1*ad1);
    if(lane==0){ asrc[2*r]=p0; asrc[2*r+1]=p1; adst[2*r]=q0; adst[2*r+1]=q1; }
  }
}

// ---------------- K10/K12: GAT aggregate (packed-bf16 xh2 gather) + spread stats ----------------
__global__ __launch_bounds__(256) void gat_agg_kernel(const unsigned* __restrict__ xh2p,
    const float2* __restrict__ asrc, const float2* __restrict__ adst,
    const int* __restrict__ offs, const int2* __restrict__ slot2,
    const float* __restrict__ coefs, int layer, const float* __restrict__ bias,
    float* __restrict__ g, float* __restrict__ spart){
  __shared__ float4 stg[4][64];
  __shared__ float s1[64], s2[64];
  int t=threadIdx.x;
  int lane=t&63, wv=t>>6;
  if(t<64){ s1[t]=0.f; s2[t]=0.f; }
  __syncthreads();
  int n=blockIdx.x*4+wv;
  float A00=coefs[16+layer*2+0], A01=coefs[16+layer*2+1];
  float A10=coefs[20+layer*2+0], A11=coefs[20+layer*2+1];
  int beg=offs[n], end=offs[n+1];
  float2 adn=adst[n];
  float s0=0.f,sB=0.f,acc0=0.f,acc1=0.f;
  for(int c0=beg;c0<end;c0+=64){
    int j=c0+lane;
    float ex0=0.f,ex1=0.f; int s=0;
    if(j<end){
      int2 sl=slot2[j];
      s=sl.x;
      unsigned p=(unsigned)sl.y;
      float e0=__uint_as_float(p<<16);
      float e1=__uint_as_float(p&0xffff0000u);
      float2 a=asrc[s];
      ex0=__expf(lrelu(a.x+adn.x+e0*A00+e1*A10));
      ex1=__expf(lrelu(a.y+adn.y+e0*A01+e1*A11));
    }
    s0+=ex0; sB+=ex1;
    stg[wv][lane]=make_float4(__int_as_float(s),ex0,ex1,0.f);
    int cnt=min(64,end-c0);
    int k=0;
    for(; k+4<=cnt; k+=4){
      float4 w0=stg[wv][k], w1=stg[wv][k+1], w2=stg[wv][k+2], w3=stg[wv][k+3];
      unsigned p0=xh2p[(size_t)__float_as_int(w0.x)*64+lane];
      unsigned p1=xh2p[(size_t)__float_as_int(w1.x)*64+lane];
      unsigned p2=xh2p[(size_t)__float_as_int(w2.x)*64+lane];
      unsigned p3=xh2p[(size_t)__float_as_int(w3.x)*64+lane];
      acc0 += w0.y*__uint_as_float(p0<<16) + w1.y*__uint_as_float(p1<<16)
            + w2.y*__uint_as_float(p2<<16) + w3.y*__uint_as_float(p3<<16);
      acc1 += w0.z*__uint_as_float(p0&0xffff0000u) + w1.z*__uint_as_float(p1&0xffff0000u)
            + w2.z*__uint_as_float(p2&0xffff0000u) + w3.z*__uint_as_float(p3&0xffff0000u);
    }
    for(; k<cnt; k++){
      float4 ws=stg[wv][k];
      unsigned pv=xh2p[(size_t)__float_as_int(ws.x)*64+lane];
      acc0 += ws.y*__uint_as_float(pv<<16);
      acc1 += ws.z*__uint_as_float(pv&0xffff0000u);
    }
  }
  s0=wred_sum(s0); sB=wred_sum(sB);
  float gv = 0.5f*(acc0/(s0+1e-16f)+acc1/(sB+1e-16f))+bias[lane];
  g[(size_t)n*64+lane]=gv;
  atomicAdd(&s1[lane],gv);
  atomicAdd(&s2[lane],gv*gv);
  __syncthreads();
  float* dstp = spart + (size_t)(blockIdx.x&(SPART-1))*128;
  if(t<64) atomicAdd(&dstp[t],s1[t]);
  else if(t<128) atomicAdd(&dstp[t],s2[t-64]);
}

// final GraphNorm+ELU -> out (float4), spart-reduce at start
__global__ __launch_bounds__(256) void gnorm_elu_kernel(const float* __restrict__ g,
    const float* __restrict__ Xin, const float* __restrict__ spart,
    const float* __restrict__ gw, const float* __restrict__ gb, const float* __restrict__ gms,
    float* __restrict__ outp){
  __shared__ float sst[2][128];
  const float invN = 1.f/(float)NTOT;
  int t=threadIdx.x;
  {
    int d=t&127, hf=t>>7;
    float a=0.f;
    for(int p=hf*64;p<hf*64+64;p++) a+=spart[p*128+d];
    sst[hf][d]=a;
  }
  __syncthreads();
  int i0=blockIdx.x*256+t;
  int d0=(i0&15)*4;
  float mmv[4],gwv[4],gbv[4];
#pragma unroll
  for(int j=0;j<4;j++){
    int d=d0+j;
    float m=(sst[0][d]+sst[1][d])*invN;
    float mm=gms[d]*m;
    mmv[j]=mm;
    gwv[j]=rsqrtf((sst[0][64+d]+sst[1][64+d])*invN-2.f*mm*m+mm*mm+1e-5f)*gw[d];
    gbv[j]=gb[d];
  }
  for(int i=i0;i<NTOT*16;i+=gridDim.x*256){
    float4 gv=((const float4*)g)[i];
    float4 xv=((const float4*)Xin)[i];
    float4 o; float z;
    z=(gv.x-mmv[0])*gwv[0]+gbv[0]+xv.x; o.x = z>0.f? z : __expf(z)-1.f;
    z=(gv.y-mmv[1])*gwv[1]+gbv[1]+xv.y; o.y = z>0.f? z : __expf(z)-1.f;
    z=(gv.z-mmv[2])*gwv[2]+gbv[2]+xv.z; o.z = z>0.f? z : __expf(z)-1.f;
    z=(gv.w-mmv[3])*gwv[3]+gbv[3]+xv.w; o.w = z>0.f? z : __expf(z)-1.f;
    ((float4*)outp)[i]=o;
  }
}

// ---------------- launch ----------------
extern "C" void kernel_launch(void* const* d_in, const int* in_sizes, int n_in,
                              void* d_out, int out_size, void* d_ws, size_t ws_size,
                              hipStream_t stream)
{
  const float* extra = (const float*)d_in[0];
  const float* user  = (const float*)d_in[1];
  const float* item  = (const float*)d_in[2];
  const float* fw1 = (const float*)d_in[3];
  const float* fb1 = (const float*)d_in[4];
  const float* fw2 = (const float*)d_in[5];
  const float* fb2 = (const float*)d_in[6];
  const float* fea = (const float*)d_in[7];
  const float* gcn_w = (const float*)d_in[8];
  const float* gcn_b = (const float*)d_in[9];
  const float* cg_lin = (const float*)d_in[10];
  const float* cg_as = (const float*)d_in[11];
  const float* cg_ad = (const float*)d_in[12];
  const float* cg_le = (const float*)d_in[13];
  const float* cg_ae = (const float*)d_in[14];
  const float* cg_bias = (const float*)d_in[15];
  const float* cea = (const float*)d_in[16];
  const float* gat_lin = (const float*)d_in[17];
  const float* gat_as = (const float*)d_in[18];
  const float* gat_ad = (const float*)d_in[19];
  const float* gat_le = (const float*)d_in[20];
  const float* gat_ae = (const float*)d_in[21];
  const float* gat_bias = (const float*)d_in[22];
  const float* gn_w = (const float*)d_in[23];
  const float* gn_b = (const float*)d_in[24];
  const float* gn_ms = (const float*)d_in[25];
  const int* fei = (const int*)d_in[26];
  const int* ca  = (const int*)d_in[27];
  const int* cei = (const int*)d_in[28];
  const int Ec = in_sizes[16]/2;
  float* outp = (float*)d_out;

  char* w = (char*)d_ws;
  auto alloc=[&](size_t b)->char*{ char* p=w; w += (b+255)&~(size_t)255; return p; };

  // zero region (single memset)
  char* z0 = w;
  int* cnt_dst = (int*)alloc((size_t)NTOT*4);
  int* degI = (int*)alloc((size_t)NTOT*4);
  int* clflag = (int*)alloc(NC*4);
  int* ccnt = (int*)alloc(NC*4);
  int* ccnt_dst = (int*)alloc(NC*4);
  float* psum = (float*)alloc((size_t)PPART*NC*64*4);
  float* spart0 = (float*)alloc((size_t)SPART*128*4);
  float* spart1 = (float*)alloc((size_t)SPART*128*4);
  size_t zbytes = (size_t)(w - z0);

  float2* partA = (float2*)alloc(2048*8);
  float2* partB = (float2*)alloc(256*8);
  float* coefs = (float*)alloc(32*4);
  int* offs = (int*)alloc((size_t)(NTOT+1)*4);
  int* incl = (int*)alloc((size_t)NTOT*4);
  int* bsum = (int*)alloc(64*4);
  int* fillptr = (int*)alloc((size_t)NTOT*4);
  int2* slot2 = (int2*)alloc((size_t)(E_EDGES+NTOT)*8);
  int* coffs = (int*)alloc((size_t)(NC+1)*4);
  int* cfillp = (int*)alloc((size_t)NC*4);
  int* cslot_src = (int*)alloc((size_t)E_EDGES*4);
  float2* cslot_ea = (float2*)alloc((size_t)E_EDGES*8);
  float* dinv = (float*)alloc((size_t)NTOT*4);
  float* xh_c = (float*)alloc(NC*256*4);
  float* asrc_c = (float*)alloc(NC*4*4);
  float* adst_c = (float*)alloc(NC*4*4);
  float* cl_upd = (float*)alloc(NC*64*4);
  float* asrc = (float*)alloc((size_t)NTOT*2*4);
  float* adst = (float*)alloc((size_t)NTOT*2*4);
  short* w1t = (short*)alloc((size_t)KSTEPS*4096*2);
  short* w2t = (short*)alloc((size_t)64*128*2);
  float* bufA = (float*)alloc((size_t)NTOT*64*4);   // X, then g
  float* bufB = (float*)alloc((size_t)NTOT*64*4);   // Xc
  float* bufC = (float*)alloc((size_t)NTOT*64*4);   // xw, then Xb
  float* bufD = (float*)alloc((size_t)NTOT*64*4);   // Xa
  unsigned* xh2p = (unsigned*)alloc((size_t)NTOT*64*4);  // packed bf16x2

  float* X  = bufA; float* g  = bufA;
  float* Xc = bufB;
  float* xw = bufC; float* Xb = bufC;
  float* Xa = bufD;

  hipMemsetAsync(z0, 0, zbytes, stream);

  prep_edges_kernel<<<PREP_GRID,256,0,stream>>>(fw1, w1t, fw2, w2t, ca,
                                              fei, fea, cnt_dst, clflag, degI, partA,
                                              cei, cea, Ec, ccnt_dst, partB);
  fus_scan_kernel<<<FUS_GRID,256,0,stream>>>(item, extra, w1t, fb1, w2t, fb2, X,
                                              partA, partB, Ec, cg_le, cg_ae, gat_le, gat_ae, coefs,
                                              cnt_dst, incl, bsum, user, ca, ccnt);
  mid_kernel<<<SC3_BLKS+1+1024,256,0,stream>>>(incl, cnt_dst, bsum, offs, fillptr, coefs, slot2,
                                              degI, dinv, ccnt_dst, coffs, cfillp,
                                              X, gcn_w, xw);
  fill_kernel<<<FILL_BLKS+128,256,0,stream>>>(fei, fea, fillptr, slot2,
                                              cei, cea, Ec, cfillp, cslot_src, cslot_ea);

  gcn_agg_kernel<<<DEG_BLKS,256,0,stream>>>(X, xw, gcn_b, offs, slot2, ca, dinv, clflag, Xc, psum);
  cluster_prep_kernel<<<NC,256,0,stream>>>(psum, ccnt, cg_lin, cg_as, cg_ad, xh_c, asrc_c, adst_c);
  cluster_agg_kernel<<<NC,256,0,stream>>>(coffs, cslot_src, cslot_ea, asrc_c, adst_c, coefs,
                                          xh_c, cg_bias, cl_upd);

  // layer 0
  gat_xh0_kernel<<<1024,256,0,stream>>>(Xc, cl_upd, ca, gat_lin, gat_as, gat_ad,
                                        xh2p, asrc, adst, Xa);
  gat_agg_kernel<<<DEG_BLKS,256,0,stream>>>(xh2p, (const float2*)asrc, (const float2*)adst,
                                            offs, slot2, coefs, 0, gat_bias, g, spart0);
  // layer 1
  gat_xh1_kernel<<<1024,256,0,stream>>>(g, Xa, spart0, gn_w, gn_b, gn_ms,
                                        gat_lin+64*128, gat_as+128, gat_ad+128,
                                        xh2p, asrc, adst, Xb);
  gat_agg_kernel<<<DEG_BLKS,256,0,stream>>>(xh2p, (const float2*)asrc, (const float2*)adst,
                                            offs, slot2, coefs, 1, gat_bias+64, g, spart1);
  gnorm_elu_kernel<<<512,256,0,stream>>>(g, Xb, spart1, gn_w+64, gn_b+64, gn_ms+64, outp);
}

// Round 10
// 648.235 us; speedup vs baseline: 3.1615x; 1.0563x over previous
//
#include <hip/hip_runtime.h>
#include <hip/hip_bf16.h>

#define N_USERS 20000
#define N_ITEMS 30000
#define NTOT    50000
#define DIM     64
#define EXTRA_D 1152
#define E_EDGES 500000
#define NC      100
#define KTOT    1216
#define KSTEPS  38
#define PPART   16
#define SPART   128

// prep_edges block ranges
#define B_FEI  1954
#define B_W1   608
#define B_W2   32
#define B_CEI  256
#define PREP_GRID (B_FEI+B_W1+B_W2+B_CEI)   // 2850

// fus_scan block ranges
#define FUS_BLKS ((N_ITEMS+127)/128)     // 235
#define SCAN1_BLKS ((NTOT+1023)/1024)    // 49
#define B_COPY 1250
#define B_CC   64
#define FUS_GRID (FUS_BLKS+SCAN1_BLKS+1+B_COPY+B_CC)  // 1599

#define SC3_BLKS ((NTOT+255)/256)        // 196
#define FILL_BLKS ((E_EDGES+255)/256)    // 1954
#define MF_XW 1024
#define MF_GRID (SC3_BLKS+1+MF_XW+FILL_BLKS+128)   // 3303
#define DEG_BLKS ((NTOT+3)/4)            // 12500 (x4 waves == NTOT exactly)

typedef __attribute__((ext_vector_type(8))) short short8;
typedef __attribute__((ext_vector_type(4))) float v4f;

// ---------------- helpers ----------------
__device__ __forceinline__ float wred_sum(float v){
#pragma unroll
  for(int o=32;o;o>>=1) v += __shfl_xor(v,o,64);
  return v;
}
__device__ __forceinline__ int wred_sumi(int v){
#pragma unroll
  for(int o=32;o;o>>=1) v += __shfl_xor(v,o,64);
  return v;
}
__device__ __forceinline__ float lrelu(float x){ return x>0.f? x : 0.2f*x; }
__device__ __forceinline__ short f2bf(float f){
  unsigned u=__float_as_uint(f);
  unsigned r=(u + 0x7FFFu + ((u>>16)&1u))>>16;
  return (short)r;
}
__device__ __forceinline__ unsigned pack_bf2(float x, float y){
  return (unsigned)(unsigned short)f2bf(x) | ((unsigned)(unsigned short)f2bf(y)<<16);
}

// ---------------- K2: prep_edges (+erank capture) ----------------
__global__ __launch_bounds__(256) void prep_edges_kernel(
    const float* __restrict__ w1, short* __restrict__ w1t,
    const float* __restrict__ w2, short* __restrict__ w2t,
    const int* __restrict__ ca,
    const int* __restrict__ fei, const float* __restrict__ fea,
    int* __restrict__ cnt_dst, int* __restrict__ clflag, int* __restrict__ degI,
    int* __restrict__ erank, float2* __restrict__ partA,
    const int* __restrict__ cei, const float* __restrict__ cea, int Ec,
    int* __restrict__ ccnt_dst, float2* __restrict__ partB)
{
  __shared__ int hist[NC];
  __shared__ float2 w4[4];
  const int b=blockIdx.x, t=threadIdx.x;
  const int lane=t&63, wv=t>>6;
  if(b < B_FEI){
    int e = b*256+t;
    float a0=0.f,a1=0.f;
    if(e<E_EDGES){
      int s=fei[e], d=fei[E_EDGES+e];
      erank[e] = atomicAdd(&cnt_dst[d],1);
      int cs=ca[s];
      if(cs==ca[d]){ clflag[cs]=1; atomicAdd(&degI[d],1); }
      float2 v=*(const float2*)(fea+2*e);
      a0=v.x; a1=v.y;
    }
    a0=wred_sum(a0); a1=wred_sum(a1);
    if(lane==0) w4[wv]=make_float2(a0,a1);
    __syncthreads();
    if(t==0){ float2 r=w4[0]; for(int i=1;i<4;i++){r.x+=w4[i].x; r.y+=w4[i].y;} partA[b]=r; }
  } else if(b < B_FEI+B_W1){
    int i = (b-B_FEI)*256+t;               // 608*256 == 1216*128 exactly
    int row = i>>7, n = i&127;             // coalesced read w1[i]
    int s = row>>5, kk = row&31;
    w1t[s*4096 + n*32 + kk] = f2bf(w1[i]);
  } else if(b < B_FEI+B_W1+B_W2){
    int i = (b-B_FEI-B_W1)*256+t;          // 32*256 == 8192 exactly
    int n = i>>6, c = i&63;                // coalesced read w2[i]
    w2t[c*128 + n] = f2bf(w2[i]);
  } else {
    int bb = b-(B_FEI+B_W1+B_W2);
    for(int i=t;i<NC;i+=256) hist[i]=0;
    __syncthreads();
    float a0=0.f,a1=0.f;
    for(int e=bb*256+t; e<Ec; e+=B_CEI*256){
      atomicAdd(&hist[cei[Ec+e]],1);
      float2 v=*(const float2*)(cea+2*e);
      a0+=v.x; a1+=v.y;
    }
    a0=wred_sum(a0); a1=wred_sum(a1);
    if(lane==0) w4[wv]=make_float2(a0,a1);
    __syncthreads();
    if(t==0){ float2 r=w4[0]; for(int i=1;i<4;i++){r.x+=w4[i].x; r.y+=w4[i].y;} partB[bb]=r; }
    for(int i=t;i<NC;i+=256) if(hist[i]) atomicAdd(&ccnt_dst[i],hist[i]);
  }
}

// ---------------- K3: fusion MFMA | scan1 | prep_small | user copy | ccnt ----------------
__global__ __launch_bounds__(256) void fus_scan_kernel(
    const float* __restrict__ item, const float* __restrict__ extra,
    const short* __restrict__ w1t, const float* __restrict__ b1,
    const short* __restrict__ w2t, const float* __restrict__ b2,
    float* __restrict__ X,
    const float2* __restrict__ partA, const float2* __restrict__ partB, int Ec,
    const float* __restrict__ cg_le, const float* __restrict__ cg_ae,
    const float* __restrict__ gat_le, const float* __restrict__ gat_ae,
    float* __restrict__ coefs,
    const int* __restrict__ cnt_dst, int* __restrict__ incl, int* __restrict__ bsum,
    const float* __restrict__ u, const int* __restrict__ ca, int* __restrict__ ccnt)
{
  __shared__ short As[128*40];
  __shared__ short Bs[128*40];
  __shared__ short Hs[128*136];
  __shared__ int ssc[256];
  const int tid = threadIdx.x;
  const int b = blockIdx.x;
  if(b < FUS_BLKS){
    const int blk = b;
    const int w = tid>>6, lane = tid&63, quad = lane>>4, l16 = lane&15;
    const int mw = w&1, nw = w>>1;

    v4f acc[4][4];
#pragma unroll
    for(int a=0;a<4;a++)
#pragma unroll
      for(int c=0;c<4;c++) acc[a][c] = (v4f){0.f,0.f,0.f,0.f};

    const int arow = tid>>3;
    const int aoff = (tid&7)*4;
    for(int s=0;s<KSTEPS;s++){
      const int k0 = s*32;
#pragma unroll
      for(int it=0;it<4;it++){
        int r = arow + it*32;
        int col = k0 + aoff;
        int gr = blk*128 + r; if(gr >= N_ITEMS) gr = N_ITEMS-1;
        float4 v = (col < DIM) ? *(const float4*)(item + (size_t)gr*DIM + col)
                               : *(const float4*)(extra + (size_t)gr*EXTRA_D + (col-DIM));
        short4 bv; bv.x=f2bf(v.x); bv.y=f2bf(v.y); bv.z=f2bf(v.z); bv.w=f2bf(v.w);
        *(short4*)&As[r*40 + aoff] = bv;
      }
#pragma unroll
      for(int it=0;it<2;it++){
        int idx = tid + it*256;
        int4 v = *(const int4*)(w1t + (size_t)s*4096 + idx*8);
        int n = idx>>2, kk = (idx&3)*8;
        *(int4*)&Bs[n*40 + kk] = v;
      }
      __syncthreads();
      short8 af[4], bf_[4];
#pragma unroll
      for(int i=0;i<4;i++){
        int m = mw*64 + i*16 + l16;
        af[i]  = *(const short8*)&As[m*40 + quad*8];
        int n = nw*64 + i*16 + l16;
        bf_[i] = *(const short8*)&Bs[n*40 + quad*8];
      }
#pragma unroll
      for(int mi=0;mi<4;mi++)
#pragma unroll
        for(int ni=0;ni<4;ni++)
          acc[mi][ni] = __builtin_amdgcn_mfma_f32_16x16x32_bf16(af[mi], bf_[ni], acc[mi][ni], 0,0,0);
      __syncthreads();
    }

#pragma unroll
    for(int ni=0;ni<4;ni++){
      int n = nw*64 + ni*16 + l16;
      float bias = b1[n];
#pragma unroll
      for(int mi=0;mi<4;mi++){
        int mbase = mw*64 + mi*16 + quad*4;
#pragma unroll
        for(int r=0;r<4;r++){
          float hv = fmaxf(acc[mi][ni][r] + bias, 0.f);
          Hs[(mbase+r)*136 + n] = f2bf(hv);
        }
      }
    }
    __syncthreads();

    v4f acc2[2][4];
#pragma unroll
    for(int a=0;a<2;a++)
#pragma unroll
      for(int c=0;c<4;c++) acc2[a][c] = (v4f){0.f,0.f,0.f,0.f};
#pragma unroll
    for(int ks=0;ks<4;ks++){
      short8 ha[2];
#pragma unroll
      for(int mi=0;mi<2;mi++){
        int m = w*32 + mi*16 + l16;
        ha[mi] = *(const short8*)&Hs[m*136 + ks*32 + quad*8];
      }
#pragma unroll
      for(int ni=0;ni<4;ni++){
        int c = ni*16 + l16;
        short8 wb = *(const short8*)(w2t + c*128 + ks*32 + quad*8);
#pragma unroll
        for(int mi=0;mi<2;mi++)
          acc2[mi][ni] = __builtin_amdgcn_mfma_f32_16x16x32_bf16(ha[mi], wb, acc2[mi][ni], 0,0,0);
      }
    }
#pragma unroll
    for(int ni=0;ni<4;ni++){
      int c = ni*16 + l16;
      float b2v = b2[c];
#pragma unroll
      for(int mi=0;mi<2;mi++){
        int mbase = w*32 + mi*16 + quad*4;
#pragma unroll
        for(int r=0;r<4;r++){
          int row = blk*128 + mbase + r;
          if(row < N_ITEMS) X[(size_t)(N_USERS+row)*64 + c] = acc2[mi][ni][r] + b2v;
        }
      }
    }
  } else if(b < FUS_BLKS+SCAN1_BLKS){
    int sb = b-FUS_BLKS;
    int base = sb*1024 + tid*4;
    int a0=(base  <NTOT)?cnt_dst[base  ]+1:0;
    int a1=(base+1<NTOT)?cnt_dst[base+1]+1:0;
    int a2=(base+2<NTOT)?cnt_dst[base+2]+1:0;
    int a3=(base+3<NTOT)?cnt_dst[base+3]+1:0;
    int l1=a0+a1, l2=l1+a2, l3=l2+a3;
    ssc[tid]=l3; __syncthreads();
    for(int off=1;off<256;off<<=1){
      int v=(tid>=off)?ssc[tid-off]:0; __syncthreads();
      ssc[tid]+=v; __syncthreads();
    }
    int prev = tid? ssc[tid-1]:0;
    if(base  <NTOT) incl[base  ]=prev+a0;
    if(base+1<NTOT) incl[base+1]=prev+l1;
    if(base+2<NTOT) incl[base+2]=prev+l2;
    if(base+3<NTOT) incl[base+3]=prev+l3;
    if(tid==255) bsum[sb]=ssc[255];
  } else if(b == FUS_BLKS+SCAN1_BLKS){
    int lane=tid&63; int wv=tid>>6;
    {
      int hh=wv;
      float v0 = cg_le[hh*64+lane]*cg_ae[hh*64+lane];
      float v1 = cg_le[256 + hh*64+lane]*cg_ae[hh*64+lane];
      v0=wred_sum(v0); v1=wred_sum(v1);
      if(lane==0){ coefs[8+hh]=v0; coefs[12+hh]=v1; }
    }
    {
      int l=wv>>1, hh=wv&1;
      float v0 = gat_le[l*256 + hh*64+lane]     * gat_ae[l*128+hh*64+lane];
      float v1 = gat_le[l*256 + 128 + hh*64+lane]* gat_ae[l*128+hh*64+lane];
      v0=wred_sum(v0); v1=wred_sum(v1);
      if(lane==0){ coefs[16+l*2+hh]=v0; coefs[20+l*2+hh]=v1; }
    }
    __syncthreads();
    if(wv==0){
      float sx=0.f, sy=0.f;
      for(int i=lane;i<B_FEI;i+=64){ float2 v=partA[i]; sx+=v.x; sy+=v.y; }
      sx=wred_sum(sx); sy=wred_sum(sy);
      if(lane==0){ coefs[4]=sx/(float)E_EDGES; coefs[5]=sy/(float)E_EDGES; }
    }
    if(wv==1){
      float sx=0.f, sy=0.f;
      for(int i=lane;i<B_CEI;i+=64){ float2 v=partB[i]; sx+=v.x; sy+=v.y; }
      sx=wred_sum(sx); sy=wred_sum(sy);
      if(lane==0){ coefs[6]=sx/(float)Ec; coefs[7]=sy/(float)Ec; }
    }
  } else if(b < FUS_BLKS+SCAN1_BLKS+1+B_COPY){
    int i = (b-FUS_BLKS-SCAN1_BLKS-1)*256+tid;
    ((float4*)X)[i] = ((const float4*)u)[i];
  } else {
    __shared__ int hist2[NC];
    int bb = b-(FUS_BLKS+SCAN1_BLKS+1+B_COPY);
    for(int i=tid;i<NC;i+=256) hist2[i]=0;
    __syncthreads();
    for(int n=bb*256+tid; n<NTOT; n+=B_CC*256) atomicAdd(&hist2[ca[n]],1);
    __syncthreads();
    for(int i=tid;i<NC;i+=256) if(hist2[i]) atomicAdd(&ccnt[i],hist2[i]);
  }
}

// ---------------- K4: midfill = scan3+dinv | cluster scan | xw | edge fill (erank) | cluster fill ----------------
__global__ __launch_bounds__(256) void midfill_kernel(
    const int* __restrict__ incl, const int* __restrict__ cnt,
    const int* __restrict__ bsum, int* __restrict__ offs,
    const float* __restrict__ coefs, int2* __restrict__ slot2,
    const int* __restrict__ degI, float* __restrict__ dinv,
    const int* __restrict__ ccnt_dst, int* __restrict__ coffs,
    const float* __restrict__ X, const float* __restrict__ gw, float* __restrict__ xw,
    const int* __restrict__ fei, const float* __restrict__ fea, const int* __restrict__ erank,
    const int* __restrict__ cei, const float* __restrict__ cea, int Ec,
    int* __restrict__ cfill0, int* __restrict__ cslot_src, float2* __restrict__ cslot_ea)
{
  __shared__ float Wl[64*64];
  __shared__ float rowb[4][64];
  __shared__ int sprev;
  __shared__ int bpref[64];
  __shared__ int hist[NC];
  __shared__ int base[NC];
  __shared__ int clpref[NC];
  const int b=blockIdx.x, t=threadIdx.x;
  if(b < SC3_BLKS){
    // scan3: offs, dinv, self-loop slot (position start+cnt)
    int blk10 = b>>2;
    if(t<64){
      int v = (t<blk10)? bsum[t] : 0;
      v = wred_sumi(v);
      if(t==0) sprev=v;
    }
    __syncthreads();
    unsigned pk = pack_bf2(coefs[4], coefs[5]);
    int i = b*256+t;
    if(i<NTOT){
      int c=cnt[i];
      int start = sprev + incl[i] - (c+1);
      offs[i]=start;
      slot2[start+c]=make_int2(i,(int)pk);
      dinv[i]=rsqrtf((float)(degI[i]+1));
    }
    if(i==0) offs[NTOT]=E_EDGES+NTOT;
  } else if(b == SC3_BLKS){
    // cluster scan -> coffs (consumed by cluster_agg in a later kernel)
    if(t<64){
      int lane=t;
      int v0 = (2*lane<NC)? ccnt_dst[2*lane]:0;
      int v1 = (2*lane+1<NC)? ccnt_dst[2*lane+1]:0;
      int pair=v0+v1;
      int sc=pair;
#pragma unroll
      for(int o=1;o<64;o<<=1){ int t2=__shfl_up(sc,o,64); if(lane>=o) sc+=t2; }
      int excl = sc - pair;
      if(2*lane<NC) coffs[2*lane]=excl;
      if(2*lane+1<NC) coffs[2*lane+1]=excl+v0;
      if(lane==63) coffs[NC]=sc;
    }
  } else if(b < SC3_BLKS+1+MF_XW){
    int bb=b-SC3_BLKS-1;
    const int lane=t&63, wv=t>>6;
    for(int i=t;i<4096;i+=256) Wl[i]=gw[i];
    __syncthreads();
    for(int r=bb*4+wv; r<NTOT; r+=MF_XW*4){
      rowb[wv][lane]=X[(size_t)r*64+lane];
      float acc=0.f;
#pragma unroll 8
      for(int k=0;k<64;k++) acc+=rowb[wv][k]*Wl[k*64+lane];
      xw[(size_t)r*64+lane]=acc;
    }
  } else if(b < SC3_BLKS+1+MF_XW+FILL_BLKS){
    // edge fill via deterministic position: bpref(chunk) + incl - cnt - 1 + erank
    if(t<64){
      int own = (t<SCAN1_BLKS)? bsum[t]:0;
      int v=own;
#pragma unroll
      for(int o=1;o<64;o<<=1){ int q=__shfl_up(v,o,64); if(t>=o) v+=q; }
      bpref[t]=v-own;
    }
    __syncthreads();
    int e = (b-(SC3_BLKS+1+MF_XW))*256+t;
    if(e<E_EDGES){
      int dst=fei[E_EDGES+e], src=fei[e];
      int start = bpref[dst>>10] + incl[dst] - cnt[dst] - 1;
      float2 v=*(const float2*)(fea+2*e);
      slot2[start + erank[e]]=make_int2(src,(int)pack_bf2(v.x,v.y));
    }
  } else {
    // cluster-edge fill: local prefix of ccnt_dst + zeroed cfill0 for inter-block bases
    if(t<64){
      int lane=t;
      int v0 = (2*lane<NC)? ccnt_dst[2*lane]:0;
      int v1 = (2*lane+1<NC)? ccnt_dst[2*lane+1]:0;
      int pair=v0+v1;
      int sc=pair;
#pragma unroll
      for(int o=1;o<64;o<<=1){ int t2=__shfl_up(sc,o,64); if(lane>=o) sc+=t2; }
      int excl = sc - pair;
      if(2*lane<NC) clpref[2*lane]=excl;
      if(2*lane+1<NC) clpref[2*lane+1]=excl+v0;
    }
    int bb=b-(SC3_BLKS+1+MF_XW+FILL_BLKS);
    const int chunk=(Ec+127)/128;
    const int beg=bb*chunk;
    const int end=min(beg+chunk,Ec);
    for(int i=t;i<NC;i+=256) hist[i]=0;
    __syncthreads();
    for(int e=beg+t;e<end;e+=256) atomicAdd(&hist[cei[Ec+e]],1);
    __syncthreads();
    for(int i=t;i<NC;i+=256){
      int h=hist[i];
      base[i] = clpref[i] + (h ? atomicAdd(&cfill0[i],h) : 0);
      hist[i]=0;
    }
    __syncthreads();
    for(int e=beg+t;e<end;e+=256){
      int d=cei[Ec+e];
      int pos = base[d] + atomicAdd(&hist[d],1);
      cslot_src[pos]=cei[e];
      cslot_ea[pos]=make_float2(cea[2*e],cea[2*e+1]);
    }
  }
}

// ---------------- K5: GCN aggregate (ballot-sparse) ----------------
__global__ __launch_bounds__(256) void gcn_agg_kernel(const float* __restrict__ X,
    const float* __restrict__ xw, const float* __restrict__ gcn_b,
    const int* __restrict__ offs, const int2* __restrict__ slot2, const int* __restrict__ ca,
    const float* __restrict__ dinv, const int* __restrict__ flag,
    float* __restrict__ Xc, float* __restrict__ psum){
  __shared__ float2 stg[4][64];
  int lane=threadIdx.x&63, wv=threadIdx.x>>6;
  int n=blockIdx.x*4+wv;
  int beg=offs[n], end=offs[n+1], myca=ca[n];
  float acc=0.f;
  for(int c0=beg;c0<end;c0+=64){
    int j=c0+lane;
    float coef=0.f; int s=0;
    if(j<end){
      s=slot2[j].x;
      if(ca[s]==myca) coef=dinv[s];
    }
    stg[wv][lane]=make_float2(__int_as_float(s),coef);
    unsigned long long bal=__ballot(coef!=0.f);
    while(bal){
      int k=__builtin_ctzll(bal); bal&=bal-1;
      float2 sc=stg[wv][k];
      acc += sc.y * xw[(size_t)__float_as_int(sc.x)*64+lane];
    }
  }
  float gout = dinv[n]*acc + gcn_b[lane];
  float xc = flag[myca] ? gout : X[(size_t)n*64+lane];
  Xc[(size_t)n*64+lane]=xc;
  atomicAdd(&psum[(size_t)(blockIdx.x&(PPART-1))*NC*64 + myca*64+lane], xc);
}

// ---------------- K6: cluster prep (pooled + xh_c + att) ----------------
__global__ __launch_bounds__(256) void cluster_prep_kernel(const float* __restrict__ psum,
    const int* __restrict__ ccnt, const float* __restrict__ cg_lin,
    const float* __restrict__ as_, const float* __restrict__ ad_,
    float* __restrict__ xh_c, float* __restrict__ asrc_c, float* __restrict__ adst_c){
  __shared__ float prow[64];
  const int c=blockIdx.x, t=threadIdx.x;
  if(t<64){
    float a=0.f;
#pragma unroll
    for(int p=0;p<PPART;p++) a += psum[(size_t)p*NC*64 + c*64 + t];
    prow[t]=a/fmaxf((float)ccnt[c],1.f);
  }
  __syncthreads();
  float acc=0.f;
#pragma unroll 8
  for(int k=0;k<64;k++) acc += prow[k]*cg_lin[k*256+t];
  xh_c[c*256+t]=acc;
  int lane=t&63, hh=t>>6;
  float s=wred_sum(acc*as_[hh*64+lane]);
  float d=wred_sum(acc*ad_[hh*64+lane]);
  if(lane==0){ asrc_c[c*4+hh]=s; adst_c[c*4+hh]=d; }
}
// ---------------- K7: cluster GAT aggregate ----------------
__global__ __launch_bounds__(256) void cluster_agg_kernel(
    const int* __restrict__ coffs, const int* __restrict__ cslot_src, const float2* __restrict__ cslot_ea,
    const float* __restrict__ asrc_c, const float* __restrict__ adst_c, const float* __restrict__ coefs,
    const float* __restrict__ xh_c, const float* __restrict__ cg_bias, float* __restrict__ cl_upd)
{
  __shared__ float sas[NC*4];
  __shared__ float sW[NC*4];
  __shared__ float ssum[4];
  __shared__ float red[4][64];
  const int c=blockIdx.x, t=threadIdx.x;
  for(int i=t;i<NC*4;i+=256){ sas[i]=asrc_c[i]; sW[i]=0.f; }
  __syncthreads();
  float ad[4], A0[4], A1[4];
#pragma unroll
  for(int h=0;h<4;h++){ ad[h]=adst_c[c*4+h]; A0[h]=coefs[8+h]; A1[h]=coefs[12+h]; }
  const int beg=coffs[c], end=coffs[c+1];
  for(int j=beg+t;j<end;j+=256){
    int s=cslot_src[j]; float2 e=cslot_ea[j];
#pragma unroll
    for(int h=0;h<4;h++){
      float al=lrelu(sas[s*4+h]+ad[h]+e.x*A0[h]+e.y*A1[h]);
      atomicAdd(&sW[s*4+h], __expf(al));
    }
  }
  if(t<4){
    float al=lrelu(sas[c*4+t]+ad[t]+coefs[6]*A0[t]+coefs[7]*A1[t]);
    atomicAdd(&sW[c*4+t], __expf(al));
  }
  __syncthreads();
  const int h=t>>6, lane=t&63;
  float p=0.f;
  if(lane<NC)    p += sW[lane*4+h];
  if(lane+64<NC) p += sW[(lane+64)*4+h];
  p=wred_sum(p);
  if(lane==0) ssum[h]=p+1e-16f;
  __syncthreads();
  float inv=1.f/ssum[h];
  float acc=0.f;
  for(int s=0;s<NC;s++) acc += sW[s*4+h]*xh_c[s*256+h*64+lane];
  red[h][lane]=acc*inv;
  __syncthreads();
  if(t<64) cl_upd[c*64+t]=0.25f*(red[0][t]+red[1][t]+red[2][t]+red[3][t])+cg_bias[t];
}

// ---------------- K8: GAT layer 0 xh (fused xcomb; xh2 packed bf16x2) ----------------
__global__ __launch_bounds__(256) void gat_xh0_kernel(const float* __restrict__ Xc,
    const float* __restrict__ cl_upd, const int* __restrict__ ca,
    const float* __restrict__ lin, const float* __restrict__ att_s, const float* __restrict__ att_d,
    unsigned* __restrict__ xh2p, float* __restrict__ asrc, float* __restrict__ adst,
    float* __restrict__ Xa){
  __shared__ __align__(16) float Wl[64*128];
  __shared__ float rowb[4][64];
  int t=threadIdx.x;
  for(int i=t;i<8192;i+=256) Wl[i]=lin[i];
  __syncthreads();
  int lane=t&63, wv=t>>6;
  float as0=att_s[lane], as1=att_s[64+lane], ad0=att_d[lane], ad1=att_d[64+lane];
  for(int r=blockIdx.x*4+wv; r<NTOT; r+=gridDim.x*4){
    float xv = Xc[(size_t)r*64+lane] + cl_upd[ca[r]*64+lane];
    Xa[(size_t)r*64+lane]=xv;
    rowb[wv][lane]=xv;
    float x0=0.f,x1=0.f;
#pragma unroll 8
    for(int k=0;k<64;k++){ float q=rowb[wv][k]; x0+=q*Wl[k*128+lane]; x1+=q*Wl[k*128+64+lane]; }
    xh2p[(size_t)r*64+lane]=pack_bf2(x0,x1);
    float p0=wred_sum(x0*as0);
    float p1=wred_sum(x1*as1);
    float q0=wred_sum(x0*ad0);
    float q1=wred_sum(x1*ad1);
    if(lane==0){ asrc[2*r]=p0; asrc[2*r+1]=p1; adst[2*r]=q0; adst[2*r+1]=q1; }
  }
}
// ---------------- K10: GAT layer 1 xh (fused GraphNorm+ELU, spart-reduce; xh2 packed) ----------------
__global__ __launch_bounds__(256) void gat_xh1_kernel(const float* __restrict__ g,
    const float* __restrict__ Xres, const float* __restrict__ spart,
    const float* __restrict__ gnw, const float* __restrict__ gnb, const float* __restrict__ gnms,
    const float* __restrict__ lin, const float* __restrict__ att_s, const float* __restrict__ att_d,
    unsigned* __restrict__ xh2p, float* __restrict__ asrc, float* __restrict__ adst,
    float* __restrict__ Xb){
  __shared__ __align__(16) float Wl[64*128];
  __shared__ float rowb[4][64];
  __shared__ float sm[4][64], sv[4][64];
  int t=threadIdx.x;
  int lane=t&63, wv=t>>6;
  for(int i=t;i<8192;i+=256) Wl[i]=lin[i];
  {
    float a0=0.f,a1=0.f;
    for(int p=wv;p<SPART;p+=4){ a0+=spart[p*128+lane]; a1+=spart[p*128+64+lane]; }
    sm[wv][lane]=a0; sv[wv][lane]=a1;
  }
  __syncthreads();
  const float invN = 1.f/(float)NTOT;
  float m=(sm[0][lane]+sm[1][lane]+sm[2][lane]+sm[3][lane])*invN;
  float vsum=(sv[0][lane]+sv[1][lane]+sv[2][lane]+sv[3][lane])*invN;
  float mm=gnms[lane]*m;
  float gwv=rsqrtf(vsum - 2.f*mm*m + mm*mm + 1e-5f)*gnw[lane];
  float gbv=gnb[lane];
  float as0=att_s[lane], as1=att_s[64+lane], ad0=att_d[lane], ad1=att_d[64+lane];
  for(int r=blockIdx.x*4+wv; r<NTOT; r+=gridDim.x*4){
    float z=(g[(size_t)r*64+lane]-mm)*gwv+gbv + Xres[(size_t)r*64+lane];
    float xv = z>0.f? z : __expf(z)-1.f;
    Xb[(size_t)r*64+lane]=xv;
    rowb[wv][lane]=xv;
    float x0=0.f,x1=0.f;
#pragma unroll 8
    for(int k=0;k<64;k++){ float q=rowb[wv][k]; x0+=q*Wl[k*128+lane]; x1+=q*Wl[k*128+64+lane]; }
    xh2p[(size_t)r*64+lane]=pack_bf2(x0,x1);
    float p0=wred_sum(x0*as0);
    float p1=wred_sum(x1*as1);
    float q0=wred_sum(x0*ad0);
    float q1=wred_sum(x1*ad1);
    if(lane==0){ asrc[2*r]=p0; asrc[2*r+1]=p1; adst[2*r]=q0; adst[2*r+1]=q1; }
  }
}

// ---------------- K9/K11: GAT aggregate (packed-bf16 xh2 gather) + spread stats ----------------
__global__ __launch_bounds__(256) void gat_agg_kernel(const unsigned* __restrict__ xh2p,
    const float2* __restrict__ asrc, const float2* __restrict__ adst,
    const int* __restrict__ offs, const int2* __restrict__ slot2,
    const float* __restrict__ coefs, int layer, const float* __restrict__ bias,
    float* __restrict__ g, float* __restrict__ spart){
  __shared__ float4 stg[4][64];
  __shared__ float s1[64], s2[64];
  int t=threadIdx.x;
  int lane=t&63, wv=t>>6;
  if(t<64){ s1[t]=0.f; s2[t]=0.f; }
  __syncthreads();
  int n=blockIdx.x*4+wv;
  float A00=coefs[16+layer*2+0], A01=coefs[16+layer*2+1];
  float A10=coefs[20+layer*2+0], A11=coefs[20+layer*2+1];
  int beg=offs[n], end=offs[n+1];
  float2 adn=adst[n];
  float s0=0.f,sB=0.f,acc0=0.f,acc1=0.f;
  for(int c0=beg;c0<end;c0+=64){
    int j=c0+lane;
    float ex0=0.f,ex1=0.f; int s=0;
    if(j<end){
      int2 sl=slot2[j];
      s=sl.x;
      unsigned p=(unsigned)sl.y;
      float e0=__uint_as_float(p<<16);
      float e1=__uint_as_float(p&0xffff0000u);
      float2 a=asrc[s];
      ex0=__expf(lrelu(a.x+adn.x+e0*A00+e1*A10));
      ex1=__expf(lrelu(a.y+adn.y+e0*A01+e1*A11));
    }
    s0+=ex0; sB+=ex1;
    stg[wv][lane]=make_float4(__int_as_float(s),ex0,ex1,0.f);
    int cnt=min(64,end-c0);
    int k=0;
    for(; k+4<=cnt; k+=4){
      float4 w0=stg[wv][k], w1=stg[wv][k+1], w2=stg[wv][k+2], w3=stg[wv][k+3];
      unsigned p0=xh2p[(size_t)__float_as_int(w0.x)*64+lane];
      unsigned p1=xh2p[(size_t)__float_as_int(w1.x)*64+lane];
      unsigned p2=xh2p[(size_t)__float_as_int(w2.x)*64+lane];
      unsigned p3=xh2p[(size_t)__float_as_int(w3.x)*64+lane];
      acc0 += w0.y*__uint_as_float(p0<<16) + w1.y*__uint_as_float(p1<<16)
            + w2.y*__uint_as_float(p2<<16) + w3.y*__uint_as_float(p3<<16);
      acc1 += w0.z*__uint_as_float(p0&0xffff0000u) + w1.z*__uint_as_float(p1&0xffff0000u)
            + w2.z*__uint_as_float(p2&0xffff0000u) + w3.z*__uint_as_float(p3&0xffff0000u);
    }
    for(; k<cnt; k++){
      float4 ws=stg[wv][k];
      unsigned pv=xh2p[(size_t)__float_as_int(ws.x)*64+lane];
      acc0 += ws.y*__uint_as_float(pv<<16);
      acc1 += ws.z*__uint_as_float(pv&0xffff0000u);
    }
  }
  s0=wred_sum(s0); sB=wred_sum(sB);
  float gv = 0.5f*(acc0/(s0+1e-16f)+acc1/(sB+1e-16f))+bias[lane];
  g[(size_t)n*64+lane]=gv;
  atomicAdd(&s1[lane],gv);
  atomicAdd(&s2[lane],gv*gv);
  __syncthreads();
  float* dstp = spart + (size_t)(blockIdx.x&(SPART-1))*128;
  if(t<64) atomicAdd(&dstp[t],s1[t]);
  else if(t<128) atomicAdd(&dstp[t],s2[t-64]);
}

// final GraphNorm+ELU -> out (float4), spart-reduce at start
__global__ __launch_bounds__(256) void gnorm_elu_kernel(const float* __restrict__ g,
    const float* __restrict__ Xin, const float* __restrict__ spart,
    const float* __restrict__ gw, const float* __restrict__ gb, const float* __restrict__ gms,
    float* __restrict__ outp){
  __shared__ float sst[2][128];
  const float invN = 1.f/(float)NTOT;
  int t=threadIdx.x;
  {
    int d=t&127, hf=t>>7;
    float a=0.f;
    for(int p=hf*64;p<hf*64+64;p++) a+=spart[p*128+d];
    sst[hf][d]=a;
  }
  __syncthreads();
  int i0=blockIdx.x*256+t;
  int d0=(i0&15)*4;
  float mmv[4],gwv[4],gbv[4];
#pragma unroll
  for(int j=0;j<4;j++){
    int d=d0+j;
    float m=(sst[0][d]+sst[1][d])*invN;
    float mm=gms[d]*m;
    mmv[j]=mm;
    gwv[j]=rsqrtf((sst[0][64+d]+sst[1][64+d])*invN-2.f*mm*m+mm*mm+1e-5f)*gw[d];
    gbv[j]=gb[d];
  }
  for(int i=i0;i<NTOT*16;i+=gridDim.x*256){
    float4 gv=((const float4*)g)[i];
    float4 xv=((const float4*)Xin)[i];
    float4 o; float z;
    z=(gv.x-mmv[0])*gwv[0]+gbv[0]+xv.x; o.x = z>0.f? z : __expf(z)-1.f;
    z=(gv.y-mmv[1])*gwv[1]+gbv[1]+xv.y; o.y = z>0.f? z : __expf(z)-1.f;
    z=(gv.z-mmv[2])*gwv[2]+gbv[2]+xv.z; o.z = z>0.f? z : __expf(z)-1.f;
    z=(gv.w-mmv[3])*gwv[3]+gbv[3]+xv.w; o.w = z>0.f? z : __expf(z)-1.f;
    ((float4*)outp)[i]=o;
  }
}

// ---------------- launch ----------------
extern "C" void kernel_launch(void* const* d_in, const int* in_sizes, int n_in,
                              void* d_out, int out_size, void* d_ws, size_t ws_size,
                              hipStream_t stream)
{
  const float* extra = (const float*)d_in[0];
  const float* user  = (const float*)d_in[1];
  const float* item  = (const float*)d_in[2];
  const float* fw1 = (const float*)d_in[3];
  const float* fb1 = (const float*)d_in[4];
  const float* fw2 = (const float*)d_in[5];
  const float* fb2 = (const float*)d_in[6];
  const float* fea = (const float*)d_in[7];
  const float* gcn_w = (const float*)d_in[8];
  const float* gcn_b = (const float*)d_in[9];
  const float* cg_lin = (const float*)d_in[10];
  const float* cg_as = (const float*)d_in[11];
  const float* cg_ad = (const float*)d_in[12];
  const float* cg_le = (const float*)d_in[13];
  const float* cg_ae = (const float*)d_in[14];
  const float* cg_bias = (const float*)d_in[15];
  const float* cea = (const float*)d_in[16];
  const float* gat_lin = (const float*)d_in[17];
  const float* gat_as = (const float*)d_in[18];
  const float* gat_ad = (const float*)d_in[19];
  const float* gat_le = (const float*)d_in[20];
  const float* gat_ae = (const float*)d_in[21];
  const float* gat_bias = (const float*)d_in[22];
  const float* gn_w = (const float*)d_in[23];
  const float* gn_b = (const float*)d_in[24];
  const float* gn_ms = (const float*)d_in[25];
  const int* fei = (const int*)d_in[26];
  const int* ca  = (const int*)d_in[27];
  const int* cei = (const int*)d_in[28];
  const int Ec = in_sizes[16]/2;
  float* outp = (float*)d_out;

  char* w = (char*)d_ws;
  auto alloc=[&](size_t b)->char*{ char* p=w; w += (b+255)&~(size_t)255; return p; };

  // zero region (single memset)
  char* z0 = w;
  int* cnt_dst = (int*)alloc((size_t)NTOT*4);
  int* degI = (int*)alloc((size_t)NTOT*4);
  int* clflag = (int*)alloc(NC*4);
  int* ccnt = (int*)alloc(NC*4);
  int* ccnt_dst = (int*)alloc(NC*4);
  int* cfill0 = (int*)alloc(NC*4);
  float* psum = (float*)alloc((size_t)PPART*NC*64*4);
  float* spart0 = (float*)alloc((size_t)SPART*128*4);
  float* spart1 = (float*)alloc((size_t)SPART*128*4);
  size_t zbytes = (size_t)(w - z0);

  float2* partA = (float2*)alloc(2048*8);
  float2* partB = (float2*)alloc(256*8);
  float* coefs = (float*)alloc(32*4);
  int* offs = (int*)alloc((size_t)(NTOT+1)*4);
  int* incl = (int*)alloc((size_t)NTOT*4);
  int* bsum = (int*)alloc(64*4);
  int* erank = (int*)alloc((size_t)E_EDGES*4);
  int2* slot2 = (int2*)alloc((size_t)(E_EDGES+NTOT)*8);
  int* coffs = (int*)alloc((size_t)(NC+1)*4);
  int* cslot_src = (int*)alloc((size_t)E_EDGES*4);
  float2* cslot_ea = (float2*)alloc((size_t)E_EDGES*8);
  float* dinv = (float*)alloc((size_t)NTOT*4);
  float* xh_c = (float*)alloc(NC*256*4);
  float* asrc_c = (float*)alloc(NC*4*4);
  float* adst_c = (float*)alloc(NC*4*4);
  float* cl_upd = (float*)alloc(NC*64*4);
  float* asrc = (float*)alloc((size_t)NTOT*2*4);
  float* adst = (float*)alloc((size_t)NTOT*2*4);
  short* w1t = (short*)alloc((size_t)KSTEPS*4096*2);
  short* w2t = (short*)alloc((size_t)64*128*2);
  float* bufA = (float*)alloc((size_t)NTOT*64*4);   // X, then g
  float* bufB = (float*)alloc((size_t)NTOT*64*4);   // Xc
  float* bufC = (float*)alloc((size_t)NTOT*64*4);   // xw, then Xb
  float* bufD = (float*)alloc((size_t)NTOT*64*4);   // Xa
  unsigned* xh2p = (unsigned*)alloc((size_t)NTOT*64*4);  // packed bf16x2

  float* X  = bufA; float* g  = bufA;
  float* Xc = bufB;
  float* xw = bufC; float* Xb = bufC;
  float* Xa = bufD;

  hipMemsetAsync(z0, 0, zbytes, stream);

  prep_edges_kernel<<<PREP_GRID,256,0,stream>>>(fw1, w1t, fw2, w2t, ca,
                                              fei, fea, cnt_dst, clflag, degI, erank, partA,
                                              cei, cea, Ec, ccnt_dst, partB);
  fus_scan_kernel<<<FUS_GRID,256,0,stream>>>(item, extra, w1t, fb1, w2t, fb2, X,
                                              partA, partB, Ec, cg_le, cg_ae, gat_le, gat_ae, coefs,
                                              cnt_dst, incl, bsum, user, ca, ccnt);
  midfill_kernel<<<MF_GRID,256,0,stream>>>(incl, cnt_dst, bsum, offs, coefs, slot2,
                                              degI, dinv, ccnt_dst, coffs,
                                              X, gcn_w, xw,
                                              fei, fea, erank,
                                              cei, cea, Ec, cfill0, cslot_src, cslot_ea);

  gcn_agg_kernel<<<DEG_BLKS,256,0,stream>>>(X, xw, gcn_b, offs, slot2, ca, dinv, clflag, Xc, psum);
  cluster_prep_kernel<<<NC,256,0,stream>>>(psum, ccnt, cg_lin, cg_as, cg_ad, xh_c, asrc_c, adst_c);
  cluster_agg_kernel<<<NC,256,0,stream>>>(coffs, cslot_src, cslot_ea, asrc_c, adst_c, coefs,
                                          xh_c, cg_bias, cl_upd);

  // layer 0
  gat_xh0_kernel<<<1024,256,0,stream>>>(Xc, cl_upd, ca, gat_lin, gat_as, gat_ad,
                                        xh2p, asrc, adst, Xa);
  gat_agg_kernel<<<DEG_BLKS,256,0,stream>>>(xh2p, (const float2*)asrc, (const float2*)adst,
                                            offs, slot2, coefs, 0, gat_bias, g, spart0);
  // layer 1
  gat_xh1_kernel<<<1024,256,0,stream>>>(g, Xa, spart0, gn_w, gn_b, gn_ms,
                                        gat_lin+64*128, gat_as+128, gat_ad+128,
                                        xh2p, asrc, adst, Xb);
  gat_agg_kernel<<<DEG_BLKS,256,0,stream>>>(xh2p, (const float2*)asrc, (const float2*)adst,
                                            offs, slot2, coefs, 1, gat_bias+64, g, spart1);
  gnorm_elu_kernel<<<512,256,0,stream>>>(g, Xb, spart1, gn_w+64, gn_b+64, gn_ms+64, outp);
}